// Round 13
// baseline (894.081 us; speedup 1.0000x reference)
//
#include <hip/hip_runtime.h>
#include <math.h>

#define NN 100000
#define NE 1600000
#define ETOT (NE + NN)
#define HEADS 8
#define NCLS 40
#define SLOPE 0.2f

#define SCAN_B 512
#define NBLK ((NN + SCAN_B - 1) / SCAN_B)   // 196

#define BW 512                    // dsts per bucket
#define NB ((NN + BW - 1) / BW)   // 196 buckets
#define EPB 8192                  // edges per bucket-pass block

#define NODEBLKS ((NN + 3) / 4)   // 25000 node-blocks (4 waves each)

typedef unsigned short ushort_t;
typedef __attribute__((ext_vector_type(8))) short short8;
typedef __attribute__((ext_vector_type(8))) _Float16 half8;
typedef __attribute__((ext_vector_type(4))) float f32x4;

static __device__ __forceinline__ ushort_t f2bf(float f) {
    unsigned u = __float_as_uint(f);
    unsigned r = (u + 0x7FFFu + ((u >> 16) & 1u)) >> 16;   // RNE
    return (ushort_t)r;
}
static __device__ __forceinline__ float bf2f(ushort_t b) {
    return __uint_as_float(((unsigned)b) << 16);
}
static __device__ __forceinline__ ushort_t f2h(float f) {
    _Float16 h = (_Float16)f;
    return __builtin_bit_cast(ushort_t, h);
}
static __device__ __forceinline__ float h2f(ushort_t u) {
    return (float)__builtin_bit_cast(_Float16, u);
}

// ----------------- CSR build -----------------
__global__ void k_init0(int* __restrict__ p, int n) {
    int i = blockIdx.x * blockDim.x + threadIdx.x;
    if (i < n) p[i] = 0;
}

__global__ void k_hist(const int* __restrict__ ei, int* __restrict__ deg) {
    int base = blockIdx.x * 1024 + threadIdx.x;
#pragma unroll
    for (int i = 0; i < 4; i++) {
        int e = base + i * 256;
        if (e < NE) {
            unsigned d = (unsigned)ei[NE + e];
            if (d < NN) atomicAdd(&deg[d], 1);   // fire-and-forget
        }
    }
}

__global__ void k_blocksum(const int* __restrict__ deg, int* __restrict__ degt,
                           int* __restrict__ bsum) {
    __shared__ int sh[SCAN_B];
    int b = blockIdx.x;
    int i = b * SCAN_B + threadIdx.x;
    int tot = 0;
    if (i < NN) {
        tot = 1 + deg[i];  // self loop
        degt[i] = tot;
    }
    sh[threadIdx.x] = tot;
    __syncthreads();
    for (int s = SCAN_B / 2; s > 0; s >>= 1) {
        if (threadIdx.x < s) sh[threadIdx.x] += sh[threadIdx.x + s];
        __syncthreads();
    }
    if (threadIdx.x == 0) bsum[b] = sh[0];
}

__global__ void k_scan_bsums(int* __restrict__ bsum, int nblk) {
    __shared__ int sh[1024];
    int t = threadIdx.x;
    int v = (t < nblk) ? bsum[t] : 0;
    sh[t] = v;
    __syncthreads();
    for (int o = 1; o < 1024; o <<= 1) {
        int add = (t >= o) ? sh[t - o] : 0;
        __syncthreads();
        sh[t] += add;
        __syncthreads();
    }
    if (t < nblk) bsum[t] = sh[t] - v;  // exclusive
}

__global__ void k_offsets(const int* __restrict__ degt, const int* __restrict__ bsum,
                          int* __restrict__ offset) {
    __shared__ int sh[SCAN_B];
    int b = blockIdx.x, t = threadIdx.x;
    int i = b * SCAN_B + t;
    int v = (i < NN) ? degt[i] : 0;
    sh[t] = v;
    __syncthreads();
    for (int o = 1; o < SCAN_B; o <<= 1) {
        int add = (t >= o) ? sh[t - o] : 0;
        __syncthreads();
        sh[t] += add;
        __syncthreads();
    }
    if (i < NN) offset[i] = sh[t] - v + bsum[b];
}

__global__ void k_initgcur(const int* __restrict__ offset, int* __restrict__ gcur) {
    int b = threadIdx.x;
    if (b < NB) gcur[b] = offset[b * BW];
}

// pass 1: partition edges into dst-range buckets, contiguous runs per block
__global__ __launch_bounds__(256) void k_bucket(const int* __restrict__ ei,
                                                int* __restrict__ gcur,
                                                uint2* __restrict__ ebuf) {
    __shared__ int cnt[NB];
    __shared__ int cnt2[NB];
    __shared__ int base[NB];
    int t = threadIdx.x;
    for (int b = t; b < NB; b += 256) { cnt[b] = 0; cnt2[b] = 0; }
    __syncthreads();
    int e0 = blockIdx.x * EPB;
#pragma unroll 4
    for (int i = 0; i < EPB / 256; i++) {
        int e = e0 + i * 256 + t;
        if (e < NE) {
            unsigned d = (unsigned)ei[NE + e];
            if (d < NN) atomicAdd(&cnt[d >> 9], 1);
        }
    }
    __syncthreads();
    for (int b = t; b < NB; b += 256) {
        base[b] = cnt[b] ? atomicAdd(&gcur[b], cnt[b]) : 0;
    }
    __syncthreads();
#pragma unroll 4
    for (int i = 0; i < EPB / 256; i++) {
        int e = e0 + i * 256 + t;
        if (e < NE) {
            unsigned d = (unsigned)ei[NE + e];
            unsigned s = (unsigned)ei[e];
            if (d < NN && s < NN) {
                int b = d >> 9;
                int r = atomicAdd(&cnt2[b], 1);
                ebuf[base[b] + r] = make_uint2(s, d);
            }
        }
    }
}

// pass 2: one block per bucket, LDS cursors, near-local csr writes
__global__ __launch_bounds__(256) void k_place(const int* __restrict__ offset,
                                               const int* __restrict__ gcur,
                                               const uint2* __restrict__ ebuf,
                                               int* __restrict__ csr_src) {
    __shared__ int lcur[BW];
    int b = blockIdx.x;
    int d0 = b * BW;
    int dN = (NN - d0 < BW) ? (NN - d0) : BW;
    int t = threadIdx.x;
    for (int i = t; i < dN; i += 256) {
        int o = offset[d0 + i];
        lcur[i] = o + 1;
        csr_src[o] = d0 + i;     // self loop
    }
    __syncthreads();
    int start = offset[d0];
    int endg = gcur[b];          // final cursor after pass 1
    for (int i = start + t; i < endg; i += 256) {
        uint2 e = ebuf[i];
        int pos = atomicAdd(&lcur[e.y - d0], 1);
        csr_src[pos] = (int)e.x;
    }
}

// ------- split W1 (bf16 hi/lo, [n][k]) + W2 (f16 hi/lo, padded [48][256]) --
__global__ void k_splitW(const float* __restrict__ W1, ushort_t* __restrict__ W1ht,
                         ushort_t* __restrict__ W1lt, const float* __restrict__ W2,
                         ushort_t* __restrict__ W2ht, ushort_t* __restrict__ W2lt) {
    if (blockIdx.x < 256) {
        int k = blockIdx.x, n = threadIdx.x;
        float v = W1[k * 256 + n];
        ushort_t hi = f2bf(v);
        ushort_t lo = f2bf(v - bf2f(hi));
        W1ht[n * 256 + k] = hi;
        W1lt[n * 256 + k] = lo;
    } else {
        int n = blockIdx.x - 256, k = threadIdx.x;
        float v = (n < NCLS) ? W2[k * NCLS + n] : 0.f;
        ushort_t hi = f2h(v);
        ushort_t lo = f2h(v - h2f(hi));
        W2ht[n * 256 + k] = hi;
        W2lt[n * 256 + k] = lo;
    }
}

// ----------------- GEMM1 (MFMA split-bf16): h1h(f16) = x @ W1; fused alphas
#define LSTR 40   // ushorts per LDS row
__global__ __launch_bounds__(256) void k_gemm1(const float* __restrict__ A,
                                               const ushort_t* __restrict__ Bht,
                                               const ushort_t* __restrict__ Blt,
                                               const float* __restrict__ attS,
                                               const float* __restrict__ attD,
                                               ushort_t* __restrict__ h1h,
                                               float* __restrict__ as1,
                                               float* __restrict__ ad1) {
    __shared__ ushort_t Ah[128 * LSTR];
    __shared__ ushort_t Al[128 * LSTR];
    __shared__ ushort_t Bh[128 * LSTR];
    __shared__ ushort_t Bl[128 * LSTR];

    int bx = blockIdx.x & 1;
    int by = blockIdx.x >> 1;
    int row0 = by * 128, col0 = bx * 128;
    int t = threadIdx.x;
    int w = t >> 6, lane = t & 63;
    int lr = lane & 15, lg = lane >> 4;
    int R0 = (w >> 1) * 64, C0 = (w & 1) * 64;

    int ar = t >> 1, ah = t & 1;          // A: row, k-half(16 f32)
    int gr_a = row0 + ar;

    f32x4 acc[4][4];
#pragma unroll
    for (int i = 0; i < 4; i++)
#pragma unroll
        for (int j = 0; j < 4; j++) acc[i][j] = (f32x4){0.f, 0.f, 0.f, 0.f};

    for (int it = 0; it < 8; it++) {
        int k0 = it * 32;
        __syncthreads();
        // ---- stage A (convert f32 -> bf16 hi/lo) ----
        {
            float f[16];
            if (gr_a < NN) {
                const float* ap = A + (size_t)gr_a * 256 + k0 + ah * 16;
#pragma unroll
                for (int i = 0; i < 4; i++) {
                    float4 v = *reinterpret_cast<const float4*>(ap + i * 4);
                    f[i * 4 + 0] = v.x; f[i * 4 + 1] = v.y; f[i * 4 + 2] = v.z; f[i * 4 + 3] = v.w;
                }
            } else {
#pragma unroll
                for (int i = 0; i < 16; i++) f[i] = 0.f;
            }
            unsigned hw[8], lw[8];
#pragma unroll
            for (int i = 0; i < 8; i++) {
                ushort_t h0 = f2bf(f[2 * i]), h1v = f2bf(f[2 * i + 1]);
                ushort_t l0 = f2bf(f[2 * i] - bf2f(h0)), l1 = f2bf(f[2 * i + 1] - bf2f(h1v));
                hw[i] = (unsigned)h0 | ((unsigned)h1v << 16);
                lw[i] = (unsigned)l0 | ((unsigned)l1 << 16);
            }
            uint4* dsth = reinterpret_cast<uint4*>(&Ah[ar * LSTR + ah * 16]);
            dsth[0] = make_uint4(hw[0], hw[1], hw[2], hw[3]);
            dsth[1] = make_uint4(hw[4], hw[5], hw[6], hw[7]);
            uint4* dstl = reinterpret_cast<uint4*>(&Al[ar * LSTR + ah * 16]);
            dstl[0] = make_uint4(lw[0], lw[1], lw[2], lw[3]);
            dstl[1] = make_uint4(lw[4], lw[5], lw[6], lw[7]);
        }
        // ---- stage B (pre-split, pre-transposed [n][k]) ----
        {
            int bn = t >> 1, bh2 = t & 1;
            const uint4* sh = reinterpret_cast<const uint4*>(Bht + (size_t)(col0 + bn) * 256 + k0 + bh2 * 16);
            const uint4* sl = reinterpret_cast<const uint4*>(Blt + (size_t)(col0 + bn) * 256 + k0 + bh2 * 16);
            uint4* dh = reinterpret_cast<uint4*>(&Bh[bn * LSTR + bh2 * 16]);
            uint4* dl = reinterpret_cast<uint4*>(&Bl[bn * LSTR + bh2 * 16]);
            dh[0] = sh[0]; dh[1] = sh[1];
            dl[0] = sl[0]; dl[1] = sl[1];
        }
        __syncthreads();
        // ---- fragments + MFMA ----
        short8 bhf[4], blf[4];
#pragma unroll
        for (int ni = 0; ni < 4; ni++) {
            int c = C0 + ni * 16 + lr;
            bhf[ni] = *reinterpret_cast<const short8*>(&Bh[c * LSTR + lg * 8]);
            blf[ni] = *reinterpret_cast<const short8*>(&Bl[c * LSTR + lg * 8]);
        }
#pragma unroll
        for (int mi = 0; mi < 4; mi++) {
            int r = R0 + mi * 16 + lr;
            short8 ahf = *reinterpret_cast<const short8*>(&Ah[r * LSTR + lg * 8]);
            short8 alf = *reinterpret_cast<const short8*>(&Al[r * LSTR + lg * 8]);
#pragma unroll
            for (int ni = 0; ni < 4; ni++) {
                acc[mi][ni] = __builtin_amdgcn_mfma_f32_16x16x32_bf16(ahf, bhf[ni], acc[mi][ni], 0, 0, 0);
                acc[mi][ni] = __builtin_amdgcn_mfma_f32_16x16x32_bf16(alf, bhf[ni], acc[mi][ni], 0, 0, 0);
                acc[mi][ni] = __builtin_amdgcn_mfma_f32_16x16x32_bf16(ahf, blf[ni], acc[mi][ni], 0, 0, 0);
            }
        }
    }

    // ---- epilogue: f16 store + fused alpha dots ----
    int cn[4];
    float sa[4], da[4];
#pragma unroll
    for (int ni = 0; ni < 4; ni++) {
        cn[ni] = col0 + C0 + ni * 16 + lr;
        sa[ni] = attS[cn[ni]];
        da[ni] = attD[cn[ni]];
    }
    int head0 = (col0 + C0) >> 5;
#pragma unroll
    for (int mi = 0; mi < 4; mi++) {
#pragma unroll
        for (int r = 0; r < 4; r++) {
            int gr = row0 + R0 + mi * 16 + lg * 4 + r;
            float v0 = acc[mi][0][r], v1 = acc[mi][1][r];
            float v2 = acc[mi][2][r], v3 = acc[mi][3][r];
            float ps0 = v0 * sa[0] + v1 * sa[1];
            float pd0 = v0 * da[0] + v1 * da[1];
            float ps1 = v2 * sa[2] + v3 * sa[3];
            float pd1 = v2 * da[2] + v3 * da[3];
#pragma unroll
            for (int m = 1; m <= 8; m <<= 1) {
                ps0 += __shfl_xor(ps0, m);
                pd0 += __shfl_xor(pd0, m);
                ps1 += __shfl_xor(ps1, m);
                pd1 += __shfl_xor(pd1, m);
            }
            if (gr < NN) {
                if (lr == 0) {
                    as1[gr * 8 + head0] = ps0;
                    ad1[gr * 8 + head0] = pd0;
                    as1[gr * 8 + head0 + 1] = ps1;
                    ad1[gr * 8 + head0 + 1] = pd1;
                }
                ushort_t* hp = h1h + (size_t)gr * 256;
                hp[cn[0]] = f2h(v0);
                hp[cn[1]] = f2h(v1);
                hp[cn[2]] = f2h(v2);
                hp[cn[3]] = f2h(v3);
            }
        }
    }
}

// ------- softmax stats + f16 weight write, layer 1: one wave/node ----------
__global__ __launch_bounds__(256) void k_soft1(const int* __restrict__ csr_src,
                                               const int* __restrict__ offset,
                                               const int* __restrict__ degt,
                                               const float* __restrict__ as1,
                                               const float* __restrict__ ad1,
                                               ushort_t* __restrict__ w1h) {
    int wave = (blockIdx.x * blockDim.x + threadIdx.x) >> 6;
    int lane = threadIdx.x & 63;
    if (wave >= NN) return;
    int d = wave;
    int sub = lane >> 3, h = lane & 7;
    float ad = ad1[d * 8 + h];
    int beg = offset[d], cnt = degt[d];
    float m = -1e30f, s = 0.f;
    for (int j = sub; j < cnt; j += 8) {
        int src = csr_src[beg + j];
        float e = as1[src * 8 + h] + ad;
        e = (e > 0.f) ? e : SLOPE * e;
        float mn = fmaxf(m, e);
        s = s * __expf(m - mn) + __expf(e - mn);
        m = mn;
    }
#pragma unroll
    for (int mask = 8; mask <= 32; mask <<= 1) {
        float mo = __shfl_xor(m, mask);
        float so = __shfl_xor(s, mask);
        float mn = fmaxf(m, mo);
        s = s * __expf(m - mn) + so * __expf(mo - mn);
        m = mn;
    }
    float di = 1.f / (s + 1e-16f);
    for (int j = sub; j < cnt; j += 8) {
        int src = csr_src[beg + j];
        float e = as1[src * 8 + h] + ad;
        e = (e > 0.f) ? e : SLOPE * e;
        w1h[(size_t)(beg + j) * 8 + h] = f2h(__expf(e - m) * di);
    }
}

// ------- aggregate pass, layer 1: PANELIZED (8 panels x 32 feats) ----------
// panel-major block order -> active h1h panel (6.4 MB) stays L2-resident.
// wave = 1 node-panel; lane = edge-slot(2b) x uint-chunk(4b).
__global__ __launch_bounds__(256) void k_agg1(const int* __restrict__ csr_src,
                                              const int* __restrict__ offset,
                                              const int* __restrict__ degt,
                                              const ushort_t* __restrict__ h1h,
                                              const ushort_t* __restrict__ w1h,
                                              const float* __restrict__ bias1,
                                              ushort_t* __restrict__ h2h) {
    int panel = blockIdx.x / NODEBLKS;        // 0..7 == head
    int nb = blockIdx.x % NODEBLKS;
    int d = nb * 4 + (threadIdx.x >> 6);
    if (d >= NN) return;
    int lane = threadIdx.x & 63;
    int es = lane >> 4;          // 4 edge slots
    int ch = lane & 15;          // 16 uints = 32 feats
    int f0 = panel * 32 + ch * 2;
    int beg = offset[d], cnt = degt[d];
    float a0 = 0.f, a1 = 0.f;
    for (int j0 = 0; j0 < cnt; j0 += 4) {
        int j = j0 + es;
        if (j < cnt) {
            int s = csr_src[beg + j];                       // slot-uniform
            float wg = h2f(w1h[(size_t)(beg + j) * 8 + panel]);  // slot-uniform
            unsigned v = *reinterpret_cast<const unsigned*>(h1h + (size_t)s * 256 + f0);
            a0 += wg * h2f((ushort_t)(v & 0xFFFFu));
            a1 += wg * h2f((ushort_t)(v >> 16));
        }
    }
    a0 += __shfl_xor(a0, 16); a0 += __shfl_xor(a0, 32);
    a1 += __shfl_xor(a1, 16); a1 += __shfl_xor(a1, 32);
    if (es == 0) {
        float v0 = a0 + bias1[f0];
        float v1 = a1 + bias1[f0 + 1];
        v0 = (v0 > 0.f) ? v0 : expm1f(v0);
        v1 = (v1 > 0.f) ? v1 : expm1f(v1);
        unsigned o = (unsigned)f2h(v0) | ((unsigned)f2h(v1) << 16);
        *reinterpret_cast<unsigned*>(h2h + (size_t)d * 256 + f0) = o;
    }
}

// ----------------- GEMM2 (MFMA f16): hh(f16) = h2h @ W2; fused alpha2 ------
__global__ __launch_bounds__(256) void k_gemm2(const ushort_t* __restrict__ A,
                                               const ushort_t* __restrict__ Bht,
                                               const ushort_t* __restrict__ Blt,
                                               const float* __restrict__ attS,
                                               const float* __restrict__ attD,
                                               ushort_t* __restrict__ hh,
                                               float* __restrict__ as2,
                                               float* __restrict__ ad2) {
    __shared__ ushort_t Ash[128 * LSTR];
    __shared__ ushort_t Bh[48 * LSTR];
    __shared__ ushort_t Bl[48 * LSTR];
    int row0 = blockIdx.x * 128;
    int t = threadIdx.x;
    int w = t >> 6, lane = t & 63;
    int lr = lane & 15, lg = lane >> 4;
    int R0 = w * 32;

    f32x4 acc[2][3];
#pragma unroll
    for (int i = 0; i < 2; i++)
#pragma unroll
        for (int j = 0; j < 3; j++) acc[i][j] = (f32x4){0.f, 0.f, 0.f, 0.f};

    for (int it = 0; it < 8; it++) {
        int k0 = it * 32;
        __syncthreads();
#pragma unroll
        for (int i = 0; i < 2; i++) {
            int chunk = t + i * 256;
            int r = chunk >> 2, part = chunk & 3;
            int gr = row0 + r;
            uint4 v = make_uint4(0u, 0u, 0u, 0u);
            if (gr < NN) v = *reinterpret_cast<const uint4*>(A + (size_t)gr * 256 + k0 + part * 8);
            *reinterpret_cast<uint4*>(&Ash[r * LSTR + part * 8]) = v;
        }
        if (t < 192) {
            int bn = t >> 2, part = t & 3;
            *reinterpret_cast<uint4*>(&Bh[bn * LSTR + part * 8]) =
                *reinterpret_cast<const uint4*>(Bht + (size_t)bn * 256 + k0 + part * 8);
            *reinterpret_cast<uint4*>(&Bl[bn * LSTR + part * 8]) =
                *reinterpret_cast<const uint4*>(Blt + (size_t)bn * 256 + k0 + part * 8);
        }
        __syncthreads();
        half8 bhf[3], blf[3];
#pragma unroll
        for (int ni = 0; ni < 3; ni++) {
            int c = ni * 16 + lr;
            bhf[ni] = *reinterpret_cast<const half8*>(&Bh[c * LSTR + lg * 8]);
            blf[ni] = *reinterpret_cast<const half8*>(&Bl[c * LSTR + lg * 8]);
        }
#pragma unroll
        for (int mi = 0; mi < 2; mi++) {
            int r = R0 + mi * 16 + lr;
            half8 af = *reinterpret_cast<const half8*>(&Ash[r * LSTR + lg * 8]);
#pragma unroll
            for (int ni = 0; ni < 3; ni++) {
                acc[mi][ni] = __builtin_amdgcn_mfma_f32_16x16x32_f16(af, bhf[ni], acc[mi][ni], 0, 0, 0);
                acc[mi][ni] = __builtin_amdgcn_mfma_f32_16x16x32_f16(af, blf[ni], acc[mi][ni], 0, 0, 0);
            }
        }
    }

    int cn[3];
    float sa[3], da[3];
#pragma unroll
    for (int ni = 0; ni < 3; ni++) {
        cn[ni] = ni * 16 + lr;
        sa[ni] = (cn[ni] < NCLS) ? attS[cn[ni]] : 0.f;
        da[ni] = (cn[ni] < NCLS) ? attD[cn[ni]] : 0.f;
    }
#pragma unroll
    for (int mi = 0; mi < 2; mi++) {
#pragma unroll
        for (int r = 0; r < 4; r++) {
            int gr = row0 + R0 + mi * 16 + lg * 4 + r;
            float v0 = acc[mi][0][r], v1 = acc[mi][1][r], v2 = acc[mi][2][r];
            float ps = v0 * sa[0] + v1 * sa[1] + v2 * sa[2];
            float pd = v0 * da[0] + v1 * da[1] + v2 * da[2];
#pragma unroll
            for (int m = 1; m <= 8; m <<= 1) {
                ps += __shfl_xor(ps, m);
                pd += __shfl_xor(pd, m);
            }
            if (gr < NN) {
                if (lr == 0) { as2[gr] = ps; ad2[gr] = pd; }
                ushort_t* hp = hh + (size_t)gr * NCLS;
                if (cn[0] < NCLS) hp[cn[0]] = f2h(v0);
                if (cn[1] < NCLS) hp[cn[1]] = f2h(v1);
                if (cn[2] < NCLS) hp[cn[2]] = f2h(v2);
            }
        }
    }
}

// ------- softmax stats + f16 weight write, layer 2: one wave/node ----------
__global__ __launch_bounds__(256) void k_soft2(const int* __restrict__ csr_src,
                                               const int* __restrict__ offset,
                                               const int* __restrict__ degt,
                                               const float* __restrict__ as2,
                                               const float* __restrict__ ad2,
                                               ushort_t* __restrict__ w2h) {
    int wave = (blockIdx.x * blockDim.x + threadIdx.x) >> 6;
    int lane = threadIdx.x & 63;
    if (wave >= NN) return;
    int d = wave;
    float ad = ad2[d];
    int beg = offset[d], cnt = degt[d];
    float m = -1e30f, s = 0.f;
    for (int j = lane; j < cnt; j += 64) {
        int src = csr_src[beg + j];
        float e = as2[src] + ad;
        e = (e > 0.f) ? e : SLOPE * e;
        float mn = fmaxf(m, e);
        s = s * __expf(m - mn) + __expf(e - mn);
        m = mn;
    }
#pragma unroll
    for (int mask = 1; mask <= 32; mask <<= 1) {
        float mo = __shfl_xor(m, mask);
        float so = __shfl_xor(s, mask);
        float mn = fmaxf(m, mo);
        s = s * __expf(m - mn) + so * __expf(mo - mn);
        m = mn;
    }
    float di = 1.f / (s + 1e-16f);
    for (int j = lane; j < cnt; j += 64) {
        int src = csr_src[beg + j];
        float e = as2[src] + ad;
        e = (e > 0.f) ? e : SLOPE * e;
        w2h[beg + j] = f2h(__expf(e - m) * di);
    }
}

// ------- aggregate pass, layer 2: 3 edges in flight, 20 lanes each ---------
__global__ __launch_bounds__(256) void k_agg2(const int* __restrict__ csr_src,
                                              const int* __restrict__ offset,
                                              const int* __restrict__ degt,
                                              const ushort_t* __restrict__ hh,
                                              const ushort_t* __restrict__ w2h,
                                              const float* __restrict__ bias2,
                                              float* __restrict__ out) {
    int wave = (blockIdx.x * blockDim.x + threadIdx.x) >> 6;
    int lane = threadIdx.x & 63;
    if (wave >= NN) return;
    int d = wave;
    int es = lane / 20;       // edge slot 0..2 (3 = idle)
    int ch = lane % 20;       // uint chunk -> classes 2ch, 2ch+1
    int beg = offset[d], cnt = degt[d];
    float a0 = 0.f, a1 = 0.f;
    for (int j0 = 0; j0 < cnt; j0 += 3) {
        int j = j0 + es;
        if (es < 3 && j < cnt) {
            int s = csr_src[beg + j];
            float w = h2f(w2h[beg + j]);
            unsigned v = *reinterpret_cast<const unsigned*>(hh + (size_t)s * NCLS + ch * 2);
            a0 += w * (float)__builtin_bit_cast(_Float16, (ushort_t)(v & 0xFFFFu));
            a1 += w * (float)__builtin_bit_cast(_Float16, (ushort_t)(v >> 16));
        }
    }
    float t0 = __shfl(a0, lane + 20);
    float t1 = __shfl(a0, lane + 40);
    float u0 = __shfl(a1, lane + 20);
    float u1 = __shfl(a1, lane + 40);
    if (lane < 20) {
        float2 o;
        o.x = a0 + t0 + t1 + bias2[ch * 2];
        o.y = a1 + u0 + u1 + bias2[ch * 2 + 1];
        *reinterpret_cast<float2*>(out + (size_t)d * NCLS + ch * 2) = o;
    }
}

extern "C" void kernel_launch(void* const* d_in, const int* in_sizes, int n_in,
                              void* d_out, int out_size, void* d_ws, size_t ws_size,
                              hipStream_t stream) {
    const float* x      = (const float*)d_in[0];
    const int* ei       = (const int*)d_in[1];   // int64 in ref -> int32 on device
    const float* W1     = (const float*)d_in[2];
    const float* att_s1 = (const float*)d_in[3];
    const float* att_d1 = (const float*)d_in[4];
    const float* bias1  = (const float*)d_in[5];
    const float* W2     = (const float*)d_in[6];
    const float* att_s2 = (const float*)d_in[7];
    const float* att_d2 = (const float*)d_in[8];
    const float* bias2  = (const float*)d_in[9];
    float* out = (float*)d_out;

    char* ws = (char*)d_ws;
    size_t off = 0;
    auto alloc = [&](size_t bytes) -> void* {
        void* p = ws + off;
        off = (off + bytes + 255) & ~(size_t)255;
        return p;
    };
    ushort_t* h1h = (ushort_t*)alloc((size_t)NN * 256 * 2);
    ushort_t* h2h = (ushort_t*)alloc((size_t)NN * 256 * 2);
    ushort_t* hh  = (ushort_t*)alloc((size_t)NN * NCLS * 2);
    float* as1  = (float*)alloc((size_t)NN * 8 * 4);
    float* ad1  = (float*)alloc((size_t)NN * 8 * 4);
    float* as2  = (float*)alloc((size_t)NN * 4);
    float* ad2  = (float*)alloc((size_t)NN * 4);
    ushort_t* w1h = (ushort_t*)alloc((size_t)ETOT * 8 * 2);
    ushort_t* w2h = (ushort_t*)alloc((size_t)ETOT * 2);
    int* deg    = (int*)alloc((size_t)NN * 4);
    int* degt   = (int*)alloc((size_t)NN * 4);
    int* offs   = (int*)alloc((size_t)(NN + 1) * 4);
    int* csr    = (int*)alloc((size_t)ETOT * 4);
    uint2* ebuf = (uint2*)alloc((size_t)ETOT * 8);
    int* gcur   = (int*)alloc((size_t)NB * 4 + 256);
    int* bsum   = (int*)alloc(4096);
    ushort_t* W1ht = (ushort_t*)alloc((size_t)256 * 256 * 2);
    ushort_t* W1lt = (ushort_t*)alloc((size_t)256 * 256 * 2);
    ushort_t* W2ht = (ushort_t*)alloc((size_t)48 * 256 * 2);
    ushort_t* W2lt = (ushort_t*)alloc((size_t)48 * 256 * 2);

    // CSR build: hist -> scan -> bucket -> place
    k_init0<<<(NN + 255) / 256, 256, 0, stream>>>(deg, NN);
    k_hist<<<(NE + 1023) / 1024, 256, 0, stream>>>(ei, deg);
    k_blocksum<<<NBLK, SCAN_B, 0, stream>>>(deg, degt, bsum);
    k_scan_bsums<<<1, 1024, 0, stream>>>(bsum, NBLK);
    k_offsets<<<NBLK, SCAN_B, 0, stream>>>(degt, bsum, offs);
    k_initgcur<<<1, 256, 0, stream>>>(offs, gcur);
    k_bucket<<<(NE + EPB - 1) / EPB, 256, 0, stream>>>(ei, gcur, ebuf);
    k_place<<<NB, 256, 0, stream>>>(offs, gcur, ebuf, csr);

    // Layer 1
    k_splitW<<<304, 256, 0, stream>>>(W1, W1ht, W1lt, W2, W2ht, W2lt);
    k_gemm1<<<((NN + 127) / 128) * 2, 256, 0, stream>>>(x, W1ht, W1lt, att_s1, att_d1, h1h, as1, ad1);
    k_soft1<<<(NN + 3) / 4, 256, 0, stream>>>(csr, offs, degt, as1, ad1, w1h);
    k_agg1<<<8 * NODEBLKS, 256, 0, stream>>>(csr, offs, degt, h1h, w1h, bias1, h2h);

    // Layer 2
    k_gemm2<<<(NN + 127) / 128, 256, 0, stream>>>(h2h, W2ht, W2lt, att_s2, att_d2, hh, as2, ad2);
    k_soft2<<<(NN + 3) / 4, 256, 0, stream>>>(csr, offs, degt, as2, ad2, w2h);
    k_agg2<<<(NN + 3) / 4, 256, 0, stream>>>(csr, offs, degt, hh, w2h, bias2, out);
}

// Round 14
// 410.571 us; speedup vs baseline: 2.1777x; 2.1777x over previous
//
#include <hip/hip_runtime.h>
#include <math.h>

#define NN 100000
#define NE 1600000
#define ETOT (NE + NN)
#define HEADS 8
#define NCLS 40
#define SLOPE 0.2f

#define BW 512                    // dsts per bucket
#define NB ((NN + BW - 1) / BW)   // 196 buckets
#define EPB 8192                  // edges per bucket-pass block
#define NBB ((NE + EPB - 1) / EPB) // 196
#define CAP 10240                 // ebuf capacity per bucket (max ~8400 expected)
#define GB1 (((NN + 127) / 128) * 2)  // 1564 gemm1 blocks

typedef unsigned short ushort_t;
typedef __attribute__((ext_vector_type(8))) short short8;
typedef __attribute__((ext_vector_type(8))) _Float16 half8;
typedef __attribute__((ext_vector_type(4))) float f32x4;

static __device__ __forceinline__ ushort_t f2bf(float f) {
    unsigned u = __float_as_uint(f);
    unsigned r = (u + 0x7FFFu + ((u >> 16) & 1u)) >> 16;   // RNE
    return (ushort_t)r;
}
static __device__ __forceinline__ float bf2f(ushort_t b) {
    return __uint_as_float(((unsigned)b) << 16);
}
static __device__ __forceinline__ ushort_t f2h(float f) {
    _Float16 h = (_Float16)f;
    return __builtin_bit_cast(ushort_t, h);
}
static __device__ __forceinline__ float h2f(ushort_t u) {
    return (float)__builtin_bit_cast(_Float16, u);
}

// ----------------- CSR build (sort-free) -----------------
__global__ void k_initbcur(int* __restrict__ bcur) {
    int b = threadIdx.x;
    if (b < NB) bcur[b] = b * CAP;
}

// partition edges into dst-range buckets at fixed-capacity regions
__global__ __launch_bounds__(256) void k_bucket2(const int* __restrict__ ei,
                                                 int* __restrict__ bcur,
                                                 uint2* __restrict__ ebuf) {
    __shared__ int cnt[NB];
    __shared__ int cnt2[NB];
    __shared__ int base[NB];
    int t = threadIdx.x;
    for (int b = t; b < NB; b += 256) { cnt[b] = 0; cnt2[b] = 0; }
    __syncthreads();
    int e0 = blockIdx.x * EPB;
#pragma unroll 4
    for (int i = 0; i < EPB / 256; i++) {
        int e = e0 + i * 256 + t;
        if (e < NE) {
            unsigned d = (unsigned)ei[NE + e];
            unsigned s = (unsigned)ei[e];
            if (d < NN && s < NN) atomicAdd(&cnt[d >> 9], 1);
        }
    }
    __syncthreads();
    for (int b = t; b < NB; b += 256) {
        base[b] = cnt[b] ? atomicAdd(&bcur[b], cnt[b]) : 0;
    }
    __syncthreads();
#pragma unroll 4
    for (int i = 0; i < EPB / 256; i++) {
        int e = e0 + i * 256 + t;
        if (e < NE) {
            unsigned d = (unsigned)ei[NE + e];
            unsigned s = (unsigned)ei[e];
            if (d < NN && s < NN) {
                int b = d >> 9;
                int r = atomicAdd(&cnt2[b], 1);
                ebuf[base[b] + r] = make_uint2(s, d);
            }
        }
    }
}

// exclusive scan of bucket totals (edges + self loops)
__global__ void k_bbase(const int* __restrict__ bcur, int* __restrict__ bbase) {
    __shared__ int sh[256];
    int t = threadIdx.x;
    int tot = 0;
    if (t < NB) {
        int dN = (NN - t * BW < BW) ? (NN - t * BW) : BW;
        tot = (bcur[t] - t * CAP) + dN;
    }
    sh[t] = tot;
    __syncthreads();
    for (int o = 1; o < 256; o <<= 1) {
        int add = (t >= o) ? sh[t - o] : 0;
        __syncthreads();
        sh[t] += add;
        __syncthreads();
    }
    if (t < NB) bbase[t] = sh[t] - tot;
}

// ------- split W1 (bf16 hi/lo, [n][k]) + W2 (f16 hi/lo, padded [48][256]) --
__global__ void k_splitW(const float* __restrict__ W1, ushort_t* __restrict__ W1ht,
                         ushort_t* __restrict__ W1lt, const float* __restrict__ W2,
                         ushort_t* __restrict__ W2ht, ushort_t* __restrict__ W2lt) {
    if (blockIdx.x < 256) {
        int k = blockIdx.x, n = threadIdx.x;
        float v = W1[k * 256 + n];
        ushort_t hi = f2bf(v);
        ushort_t lo = f2bf(v - bf2f(hi));
        W1ht[n * 256 + k] = hi;
        W1lt[n * 256 + k] = lo;
    } else {
        int n = blockIdx.x - 256, k = threadIdx.x;
        float v = (n < NCLS) ? W2[k * NCLS + n] : 0.f;
        ushort_t hi = f2h(v);
        ushort_t lo = f2h(v - h2f(hi));
        W2ht[n * 256 + k] = hi;
        W2lt[n * 256 + k] = lo;
    }
}

// ------ FUSED: GEMM1 (blocks < GB1) + CSR place (blocks >= GB1) ------------
#define LSTR 40   // ushorts per LDS row
__global__ __launch_bounds__(256) void k_gemm1s(const float* __restrict__ A,
                                                const ushort_t* __restrict__ Bht,
                                                const ushort_t* __restrict__ Blt,
                                                const float* __restrict__ attS,
                                                const float* __restrict__ attD,
                                                ushort_t* __restrict__ h1h,
                                                float* __restrict__ as1,
                                                float* __restrict__ ad1,
                                                const int* __restrict__ bcur,
                                                const int* __restrict__ bbase,
                                                const uint2* __restrict__ ebuf,
                                                int* __restrict__ offset,
                                                int* __restrict__ degt,
                                                int* __restrict__ csr_src) {
    __shared__ ushort_t Ah[128 * LSTR];
    __shared__ ushort_t Al[128 * LSTR];
    __shared__ ushort_t Bh[128 * LSTR];
    __shared__ ushort_t Bl[128 * LSTR];

    if (blockIdx.x >= GB1) {
        // ---------------- place body: derive offsets + scatter locally -----
        int b = blockIdx.x - GB1;
        int* cnt  = (int*)Ah;
        int* sA   = (int*)Al;
        int* sB   = (int*)Bh;
        int* lcur = (int*)Bl;
        int t = threadIdx.x;
        int d0 = b * BW;
        int dN = (NN - d0 < BW) ? (NN - d0) : BW;
        cnt[t] = (t < dN) ? 1 : 0;
        cnt[t + 256] = (t + 256 < dN) ? 1 : 0;
        __syncthreads();
        int bcurv = bcur[b];
        for (int i = b * CAP + t; i < bcurv; i += 256)
            atomicAdd(&cnt[ebuf[i].y - d0], 1);
        __syncthreads();
        int o0 = cnt[t], o1 = cnt[t + 256];
        sA[t] = o0; sA[t + 256] = o1;
        __syncthreads();
        int* sp = sA; int* dp = sB;
        for (int o = 1; o < 512; o <<= 1) {
            dp[t] = sp[t] + ((t >= o) ? sp[t - o] : 0);
            int t2 = t + 256;
            dp[t2] = sp[t2] + ((t2 >= o) ? sp[t2 - o] : 0);
            __syncthreads();
            int* tmp = sp; sp = dp; dp = tmp;
        }
        int base = bbase[b];
        if (t < dN) {
            int off = base + sp[t] - o0;
            offset[d0 + t] = off;
            degt[d0 + t] = o0;
            csr_src[off] = d0 + t;   // self loop
            lcur[t] = off + 1;
        }
        int t2 = t + 256;
        if (t2 < dN) {
            int off = base + sp[t2] - o1;
            offset[d0 + t2] = off;
            degt[d0 + t2] = o1;
            csr_src[off] = d0 + t2;
            lcur[t2] = off + 1;
        }
        __syncthreads();
        for (int i = b * CAP + t; i < bcurv; i += 256) {
            uint2 e = ebuf[i];
            int pos = atomicAdd(&lcur[e.y - d0], 1);
            csr_src[pos] = (int)e.x;
        }
        return;
    }

    // ---------------- GEMM body ----------------
    int bx = blockIdx.x & 1;
    int by = blockIdx.x >> 1;
    int row0 = by * 128, col0 = bx * 128;
    int t = threadIdx.x;
    int w = t >> 6, lane = t & 63;
    int lr = lane & 15, lg = lane >> 4;
    int R0 = (w >> 1) * 64, C0 = (w & 1) * 64;

    int ar = t >> 1, ah = t & 1;
    int gr_a = row0 + ar;

    f32x4 acc[4][4];
#pragma unroll
    for (int i = 0; i < 4; i++)
#pragma unroll
        for (int j = 0; j < 4; j++) acc[i][j] = (f32x4){0.f, 0.f, 0.f, 0.f};

    for (int it = 0; it < 8; it++) {
        int k0 = it * 32;
        __syncthreads();
        {
            float f[16];
            if (gr_a < NN) {
                const float* ap = A + (size_t)gr_a * 256 + k0 + ah * 16;
#pragma unroll
                for (int i = 0; i < 4; i++) {
                    float4 v = *reinterpret_cast<const float4*>(ap + i * 4);
                    f[i * 4 + 0] = v.x; f[i * 4 + 1] = v.y; f[i * 4 + 2] = v.z; f[i * 4 + 3] = v.w;
                }
            } else {
#pragma unroll
                for (int i = 0; i < 16; i++) f[i] = 0.f;
            }
            unsigned hw[8], lw[8];
#pragma unroll
            for (int i = 0; i < 8; i++) {
                ushort_t h0 = f2bf(f[2 * i]), h1v = f2bf(f[2 * i + 1]);
                ushort_t l0 = f2bf(f[2 * i] - bf2f(h0)), l1 = f2bf(f[2 * i + 1] - bf2f(h1v));
                hw[i] = (unsigned)h0 | ((unsigned)h1v << 16);
                lw[i] = (unsigned)l0 | ((unsigned)l1 << 16);
            }
            uint4* dsth = reinterpret_cast<uint4*>(&Ah[ar * LSTR + ah * 16]);
            dsth[0] = make_uint4(hw[0], hw[1], hw[2], hw[3]);
            dsth[1] = make_uint4(hw[4], hw[5], hw[6], hw[7]);
            uint4* dstl = reinterpret_cast<uint4*>(&Al[ar * LSTR + ah * 16]);
            dstl[0] = make_uint4(lw[0], lw[1], lw[2], lw[3]);
            dstl[1] = make_uint4(lw[4], lw[5], lw[6], lw[7]);
        }
        {
            int bn = t >> 1, bh2 = t & 1;
            const uint4* sh = reinterpret_cast<const uint4*>(Bht + (size_t)(col0 + bn) * 256 + k0 + bh2 * 16);
            const uint4* sl = reinterpret_cast<const uint4*>(Blt + (size_t)(col0 + bn) * 256 + k0 + bh2 * 16);
            uint4* dh = reinterpret_cast<uint4*>(&Bh[bn * LSTR + bh2 * 16]);
            uint4* dl = reinterpret_cast<uint4*>(&Bl[bn * LSTR + bh2 * 16]);
            dh[0] = sh[0]; dh[1] = sh[1];
            dl[0] = sl[0]; dl[1] = sl[1];
        }
        __syncthreads();
        short8 bhf[4], blf[4];
#pragma unroll
        for (int ni = 0; ni < 4; ni++) {
            int c = C0 + ni * 16 + lr;
            bhf[ni] = *reinterpret_cast<const short8*>(&Bh[c * LSTR + lg * 8]);
            blf[ni] = *reinterpret_cast<const short8*>(&Bl[c * LSTR + lg * 8]);
        }
#pragma unroll
        for (int mi = 0; mi < 4; mi++) {
            int r = R0 + mi * 16 + lr;
            short8 ahf = *reinterpret_cast<const short8*>(&Ah[r * LSTR + lg * 8]);
            short8 alf = *reinterpret_cast<const short8*>(&Al[r * LSTR + lg * 8]);
#pragma unroll
            for (int ni = 0; ni < 4; ni++) {
                acc[mi][ni] = __builtin_amdgcn_mfma_f32_16x16x32_bf16(ahf, bhf[ni], acc[mi][ni], 0, 0, 0);
                acc[mi][ni] = __builtin_amdgcn_mfma_f32_16x16x32_bf16(alf, bhf[ni], acc[mi][ni], 0, 0, 0);
                acc[mi][ni] = __builtin_amdgcn_mfma_f32_16x16x32_bf16(ahf, blf[ni], acc[mi][ni], 0, 0, 0);
            }
        }
    }

    int cn[4];
    float sa[4], da[4];
#pragma unroll
    for (int ni = 0; ni < 4; ni++) {
        cn[ni] = col0 + C0 + ni * 16 + lr;
        sa[ni] = attS[cn[ni]];
        da[ni] = attD[cn[ni]];
    }
    int head0 = (col0 + C0) >> 5;
#pragma unroll
    for (int mi = 0; mi < 4; mi++) {
#pragma unroll
        for (int r = 0; r < 4; r++) {
            int gr = row0 + R0 + mi * 16 + lg * 4 + r;
            float v0 = acc[mi][0][r], v1 = acc[mi][1][r];
            float v2 = acc[mi][2][r], v3 = acc[mi][3][r];
            float ps0 = v0 * sa[0] + v1 * sa[1];
            float pd0 = v0 * da[0] + v1 * da[1];
            float ps1 = v2 * sa[2] + v3 * sa[3];
            float pd1 = v2 * da[2] + v3 * da[3];
#pragma unroll
            for (int m = 1; m <= 8; m <<= 1) {
                ps0 += __shfl_xor(ps0, m);
                pd0 += __shfl_xor(pd0, m);
                ps1 += __shfl_xor(ps1, m);
                pd1 += __shfl_xor(pd1, m);
            }
            if (gr < NN) {
                if (lr == 0) {
                    as1[gr * 8 + head0] = ps0;
                    ad1[gr * 8 + head0] = pd0;
                    as1[gr * 8 + head0 + 1] = ps1;
                    ad1[gr * 8 + head0 + 1] = pd1;
                }
                ushort_t* hp = h1h + (size_t)gr * 256;
                hp[cn[0]] = f2h(v0);
                hp[cn[1]] = f2h(v1);
                hp[cn[2]] = f2h(v2);
                hp[cn[3]] = f2h(v3);
            }
        }
    }
}

// ------- softmax stats + f16 weight write, layer 1: one wave/node ----------
__global__ __launch_bounds__(256) void k_soft1(const int* __restrict__ csr_src,
                                               const int* __restrict__ offset,
                                               const int* __restrict__ degt,
                                               const float* __restrict__ as1,
                                               const float* __restrict__ ad1,
                                               ushort_t* __restrict__ w1h) {
    int wave = (blockIdx.x * blockDim.x + threadIdx.x) >> 6;
    int lane = threadIdx.x & 63;
    if (wave >= NN) return;
    int d = wave;
    int sub = lane >> 3, h = lane & 7;
    float ad = ad1[d * 8 + h];
    int beg = offset[d], cnt = degt[d];
    float m = -1e30f, s = 0.f;
    for (int j = sub; j < cnt; j += 8) {
        int src = csr_src[beg + j];
        float e = as1[src * 8 + h] + ad;
        e = (e > 0.f) ? e : SLOPE * e;
        float mn = fmaxf(m, e);
        s = s * __expf(m - mn) + __expf(e - mn);
        m = mn;
    }
#pragma unroll
    for (int mask = 8; mask <= 32; mask <<= 1) {
        float mo = __shfl_xor(m, mask);
        float so = __shfl_xor(s, mask);
        float mn = fmaxf(m, mo);
        s = s * __expf(m - mn) + so * __expf(mo - mn);
        m = mn;
    }
    float di = 1.f / (s + 1e-16f);
    for (int j = sub; j < cnt; j += 8) {
        int src = csr_src[beg + j];
        float e = as1[src * 8 + h] + ad;
        e = (e > 0.f) ? e : SLOPE * e;
        w1h[(size_t)(beg + j) * 8 + h] = f2h(__expf(e - m) * di);
    }
}

// ------- aggregate pass, layer 1: one wave/node (R12 structure) ------------
__global__ __launch_bounds__(256) void k_agg1(const int* __restrict__ csr_src,
                                              const int* __restrict__ offset,
                                              const int* __restrict__ degt,
                                              const ushort_t* __restrict__ h1h,
                                              const ushort_t* __restrict__ w1h,
                                              const float* __restrict__ bias1,
                                              ushort_t* __restrict__ h2h) {
    int wave = (blockIdx.x * blockDim.x + threadIdx.x) >> 6;
    int lane = threadIdx.x & 63;
    if (wave >= NN) return;
    int d = wave;
    int h = lane >> 3;
    int f0 = lane * 4;
    int beg = offset[d], cnt = degt[d];
    float ax = 0.f, ay = 0.f, az = 0.f, aw = 0.f;
#pragma unroll 4
    for (int j = 0; j < cnt; j++) {
        int s = csr_src[beg + j];
        float wg = h2f(w1h[(size_t)(beg + j) * 8 + h]);
        ushort4 hv = *reinterpret_cast<const ushort4*>(h1h + (size_t)s * 256 + f0);
        ax += wg * (float)__builtin_bit_cast(_Float16, hv.x);
        ay += wg * (float)__builtin_bit_cast(_Float16, hv.y);
        az += wg * (float)__builtin_bit_cast(_Float16, hv.z);
        aw += wg * (float)__builtin_bit_cast(_Float16, hv.w);
    }
    float4 b = *reinterpret_cast<const float4*>(bias1 + f0);
    float vx = ax + b.x;
    float vy = ay + b.y;
    float vz = az + b.z;
    float vw = aw + b.w;
    vx = (vx > 0.f) ? vx : expm1f(vx);
    vy = (vy > 0.f) ? vy : expm1f(vy);
    vz = (vz > 0.f) ? vz : expm1f(vz);
    vw = (vw > 0.f) ? vw : expm1f(vw);
    ushort4 o;
    o.x = f2h(vx); o.y = f2h(vy); o.z = f2h(vz); o.w = f2h(vw);
    *reinterpret_cast<ushort4*>(h2h + (size_t)d * 256 + f0) = o;
}

// ----------------- GEMM2 (MFMA f16): hh(f16) = h2h @ W2; fused alpha2 ------
__global__ __launch_bounds__(256) void k_gemm2(const ushort_t* __restrict__ A,
                                               const ushort_t* __restrict__ Bht,
                                               const ushort_t* __restrict__ Blt,
                                               const float* __restrict__ attS,
                                               const float* __restrict__ attD,
                                               ushort_t* __restrict__ hh,
                                               float* __restrict__ as2,
                                               float* __restrict__ ad2) {
    __shared__ ushort_t Ash[128 * LSTR];
    __shared__ ushort_t Bh[48 * LSTR];
    __shared__ ushort_t Bl[48 * LSTR];
    int row0 = blockIdx.x * 128;
    int t = threadIdx.x;
    int w = t >> 6, lane = t & 63;
    int lr = lane & 15, lg = lane >> 4;
    int R0 = w * 32;

    f32x4 acc[2][3];
#pragma unroll
    for (int i = 0; i < 2; i++)
#pragma unroll
        for (int j = 0; j < 3; j++) acc[i][j] = (f32x4){0.f, 0.f, 0.f, 0.f};

    for (int it = 0; it < 8; it++) {
        int k0 = it * 32;
        __syncthreads();
#pragma unroll
        for (int i = 0; i < 2; i++) {
            int chunk = t + i * 256;
            int r = chunk >> 2, part = chunk & 3;
            int gr = row0 + r;
            uint4 v = make_uint4(0u, 0u, 0u, 0u);
            if (gr < NN) v = *reinterpret_cast<const uint4*>(A + (size_t)gr * 256 + k0 + part * 8);
            *reinterpret_cast<uint4*>(&Ash[r * LSTR + part * 8]) = v;
        }
        if (t < 192) {
            int bn = t >> 2, part = t & 3;
            *reinterpret_cast<uint4*>(&Bh[bn * LSTR + part * 8]) =
                *reinterpret_cast<const uint4*>(Bht + (size_t)bn * 256 + k0 + part * 8);
            *reinterpret_cast<uint4*>(&Bl[bn * LSTR + part * 8]) =
                *reinterpret_cast<const uint4*>(Blt + (size_t)bn * 256 + k0 + part * 8);
        }
        __syncthreads();
        half8 bhf[3], blf[3];
#pragma unroll
        for (int ni = 0; ni < 3; ni++) {
            int c = ni * 16 + lr;
            bhf[ni] = *reinterpret_cast<const half8*>(&Bh[c * LSTR + lg * 8]);
            blf[ni] = *reinterpret_cast<const half8*>(&Bl[c * LSTR + lg * 8]);
        }
#pragma unroll
        for (int mi = 0; mi < 2; mi++) {
            int r = R0 + mi * 16 + lr;
            half8 af = *reinterpret_cast<const half8*>(&Ash[r * LSTR + lg * 8]);
#pragma unroll
            for (int ni = 0; ni < 3; ni++) {
                acc[mi][ni] = __builtin_amdgcn_mfma_f32_16x16x32_f16(af, bhf[ni], acc[mi][ni], 0, 0, 0);
                acc[mi][ni] = __builtin_amdgcn_mfma_f32_16x16x32_f16(af, blf[ni], acc[mi][ni], 0, 0, 0);
            }
        }
    }

    int cn[3];
    float sa[3], da[3];
#pragma unroll
    for (int ni = 0; ni < 3; ni++) {
        cn[ni] = ni * 16 + lr;
        sa[ni] = (cn[ni] < NCLS) ? attS[cn[ni]] : 0.f;
        da[ni] = (cn[ni] < NCLS) ? attD[cn[ni]] : 0.f;
    }
#pragma unroll
    for (int mi = 0; mi < 2; mi++) {
#pragma unroll
        for (int r = 0; r < 4; r++) {
            int gr = row0 + R0 + mi * 16 + lg * 4 + r;
            float v0 = acc[mi][0][r], v1 = acc[mi][1][r], v2 = acc[mi][2][r];
            float ps = v0 * sa[0] + v1 * sa[1] + v2 * sa[2];
            float pd = v0 * da[0] + v1 * da[1] + v2 * da[2];
#pragma unroll
            for (int m = 1; m <= 8; m <<= 1) {
                ps += __shfl_xor(ps, m);
                pd += __shfl_xor(pd, m);
            }
            if (gr < NN) {
                if (lr == 0) { as2[gr] = ps; ad2[gr] = pd; }
                ushort_t* hp = hh + (size_t)gr * NCLS;
                if (cn[0] < NCLS) hp[cn[0]] = f2h(v0);
                if (cn[1] < NCLS) hp[cn[1]] = f2h(v1);
                if (cn[2] < NCLS) hp[cn[2]] = f2h(v2);
            }
        }
    }
}

// ------- merged softmax + aggregate, layer 2: one wave/node ----------------
__global__ __launch_bounds__(256) void k_sa2(const int* __restrict__ csr_src,
                                             const int* __restrict__ offset,
                                             const int* __restrict__ degt,
                                             const ushort_t* __restrict__ hh,
                                             const float* __restrict__ as2,
                                             const float* __restrict__ ad2,
                                             const float* __restrict__ bias2,
                                             float* __restrict__ out) {
    int wave = (blockIdx.x * blockDim.x + threadIdx.x) >> 6;
    int lane = threadIdx.x & 63;
    if (wave >= NN) return;
    int d = wave;
    float ad = ad2[d];
    int beg = offset[d], cnt = degt[d];
    // phase 1: softmax stats
    float m = -1e30f, s = 0.f;
    for (int j = lane; j < cnt; j += 64) {
        int src = csr_src[beg + j];
        float e = as2[src] + ad;
        e = (e > 0.f) ? e : SLOPE * e;
        float mn = fmaxf(m, e);
        s = s * __expf(m - mn) + __expf(e - mn);
        m = mn;
    }
#pragma unroll
    for (int mask = 1; mask <= 32; mask <<= 1) {
        float mo = __shfl_xor(m, mask);
        float so = __shfl_xor(s, mask);
        float mn = fmaxf(m, mo);
        s = s * __expf(m - mn) + so * __expf(mo - mn);
        m = mn;
    }
    float di = 1.f / (s + 1e-16f);
    // phase 2: weighted aggregate, 3 edge-slots x 20 class-chunks
    int es = lane / 20;
    int ch = lane % 20;
    float a0 = 0.f, a1 = 0.f;
    for (int j0 = 0; j0 < cnt; j0 += 3) {
        int j = j0 + es;
        if (es < 3 && j < cnt) {
            int src = csr_src[beg + j];
            float e = as2[src] + ad;
            e = (e > 0.f) ? e : SLOPE * e;
            float w = __expf(e - m) * di;
            unsigned v = *reinterpret_cast<const unsigned*>(hh + (size_t)src * NCLS + ch * 2);
            a0 += w * (float)__builtin_bit_cast(_Float16, (ushort_t)(v & 0xFFFFu));
            a1 += w * (float)__builtin_bit_cast(_Float16, (ushort_t)(v >> 16));
        }
    }
    float t0 = __shfl(a0, lane + 20);
    float t1 = __shfl(a0, lane + 40);
    float u0 = __shfl(a1, lane + 20);
    float u1 = __shfl(a1, lane + 40);
    if (lane < 20) {
        float2 o;
        o.x = a0 + t0 + t1 + bias2[ch * 2];
        o.y = a1 + u0 + u1 + bias2[ch * 2 + 1];
        *reinterpret_cast<float2*>(out + (size_t)d * NCLS + ch * 2) = o;
    }
}

extern "C" void kernel_launch(void* const* d_in, const int* in_sizes, int n_in,
                              void* d_out, int out_size, void* d_ws, size_t ws_size,
                              hipStream_t stream) {
    const float* x      = (const float*)d_in[0];
    const int* ei       = (const int*)d_in[1];   // int64 in ref -> int32 on device
    const float* W1     = (const float*)d_in[2];
    const float* att_s1 = (const float*)d_in[3];
    const float* att_d1 = (const float*)d_in[4];
    const float* bias1  = (const float*)d_in[5];
    const float* W2     = (const float*)d_in[6];
    const float* att_s2 = (const float*)d_in[7];
    const float* att_d2 = (const float*)d_in[8];
    const float* bias2  = (const float*)d_in[9];
    float* out = (float*)d_out;

    char* ws = (char*)d_ws;
    size_t off = 0;
    auto alloc = [&](size_t bytes) -> void* {
        void* p = ws + off;
        off = (off + bytes + 255) & ~(size_t)255;
        return p;
    };
    ushort_t* h1h = (ushort_t*)alloc((size_t)NN * 256 * 2);
    ushort_t* h2h = (ushort_t*)alloc((size_t)NN * 256 * 2);
    ushort_t* hh  = (ushort_t*)alloc((size_t)NN * NCLS * 2);
    float* as1  = (float*)alloc((size_t)NN * 8 * 4);
    float* ad1  = (float*)alloc((size_t)NN * 8 * 4);
    float* as2  = (float*)alloc((size_t)NN * 4);
    float* ad2  = (float*)alloc((size_t)NN * 4);
    ushort_t* w1h = (ushort_t*)alloc((size_t)ETOT * 8 * 2);
    int* degt   = (int*)alloc((size_t)NN * 4);
    int* offs   = (int*)alloc((size_t)(NN + 1) * 4);
    int* csr    = (int*)alloc((size_t)ETOT * 4);
    uint2* ebuf = (uint2*)alloc((size_t)NB * CAP * 8);
    int* bcur   = (int*)alloc((size_t)NB * 4 + 256);
    int* bbase  = (int*)alloc((size_t)NB * 4 + 256);
    ushort_t* W1ht = (ushort_t*)alloc((size_t)256 * 256 * 2);
    ushort_t* W1lt = (ushort_t*)alloc((size_t)256 * 256 * 2);
    ushort_t* W2ht = (ushort_t*)alloc((size_t)48 * 256 * 2);
    ushort_t* W2lt = (ushort_t*)alloc((size_t)48 * 256 * 2);

    // CSR build (sort-free): bucket -> base-scan -> place (fused with gemm1)
    k_initbcur<<<1, 256, 0, stream>>>(bcur);
    k_bucket2<<<NBB, 256, 0, stream>>>(ei, bcur, ebuf);
    k_bbase<<<1, 256, 0, stream>>>(bcur, bbase);

    // Layer 1
    k_splitW<<<304, 256, 0, stream>>>(W1, W1ht, W1lt, W2, W2ht, W2lt);
    k_gemm1s<<<GB1 + NB, 256, 0, stream>>>(x, W1ht, W1lt, att_s1, att_d1, h1h, as1, ad1,
                                           bcur, bbase, ebuf, offs, degt, csr);
    k_soft1<<<(NN + 3) / 4, 256, 0, stream>>>(csr, offs, degt, as1, ad1, w1h);
    k_agg1<<<(NN + 3) / 4, 256, 0, stream>>>(csr, offs, degt, h1h, w1h, bias1, h2h);

    // Layer 2
    k_gemm2<<<(NN + 127) / 128, 256, 0, stream>>>(h2h, W2ht, W2lt, att_s2, att_d2, hh, as2, ad2);
    k_sa2<<<(NN + 3) / 4, 256, 0, stream>>>(csr, offs, degt, hh, as2, ad2, bias2, out);
}

// Round 15
// 389.545 us; speedup vs baseline: 2.2952x; 1.0540x over previous
//
#include <hip/hip_runtime.h>
#include <math.h>

#define NN 100000
#define NE 1600000
#define ETOT (NE + NN)
#define HEADS 8
#define NCLS 40
#define SLOPE 0.2f

#define BW 512                    // dsts per bucket
#define NB ((NN + BW - 1) / BW)   // 196 buckets
#define EPB 8192                  // edges per bucket-pass block
#define NBB ((NE + EPB - 1) / EPB) // 196
#define CAP 10240                 // ebuf capacity per bucket (max ~8400 expected)
#define GB1 (((NN + 127) / 128) * 2)  // 1564 gemm1 blocks

typedef unsigned short ushort_t;
typedef __attribute__((ext_vector_type(8))) short short8;
typedef __attribute__((ext_vector_type(8))) _Float16 half8;
typedef __attribute__((ext_vector_type(4))) float f32x4;

static __device__ __forceinline__ ushort_t f2bf(float f) {
    unsigned u = __float_as_uint(f);
    unsigned r = (u + 0x7FFFu + ((u >> 16) & 1u)) >> 16;   // RNE
    return (ushort_t)r;
}
static __device__ __forceinline__ float bf2f(ushort_t b) {
    return __uint_as_float(((unsigned)b) << 16);
}
static __device__ __forceinline__ ushort_t f2h(float f) {
    _Float16 h = (_Float16)f;
    return __builtin_bit_cast(ushort_t, h);
}
static __device__ __forceinline__ float h2f(ushort_t u) {
    return (float)__builtin_bit_cast(_Float16, u);
}

// ----------------- CSR build (sort-free) -----------------
__global__ void k_initbcur(int* __restrict__ bcur) {
    int b = threadIdx.x;
    if (b < NB) bcur[b] = b * CAP;
}

__global__ __launch_bounds__(256) void k_bucket2(const int* __restrict__ ei,
                                                 int* __restrict__ bcur,
                                                 uint2* __restrict__ ebuf) {
    __shared__ int cnt[NB];
    __shared__ int cnt2[NB];
    __shared__ int base[NB];
    int t = threadIdx.x;
    for (int b = t; b < NB; b += 256) { cnt[b] = 0; cnt2[b] = 0; }
    __syncthreads();
    int e0 = blockIdx.x * EPB;
#pragma unroll 4
    for (int i = 0; i < EPB / 256; i++) {
        int e = e0 + i * 256 + t;
        if (e < NE) {
            unsigned d = (unsigned)ei[NE + e];
            unsigned s = (unsigned)ei[e];
            if (d < NN && s < NN) atomicAdd(&cnt[d >> 9], 1);
        }
    }
    __syncthreads();
    for (int b = t; b < NB; b += 256) {
        base[b] = cnt[b] ? atomicAdd(&bcur[b], cnt[b]) : 0;
    }
    __syncthreads();
#pragma unroll 4
    for (int i = 0; i < EPB / 256; i++) {
        int e = e0 + i * 256 + t;
        if (e < NE) {
            unsigned d = (unsigned)ei[NE + e];
            unsigned s = (unsigned)ei[e];
            if (d < NN && s < NN) {
                int b = d >> 9;
                int r = atomicAdd(&cnt2[b], 1);
                ebuf[base[b] + r] = make_uint2(s, d);
            }
        }
    }
}

__global__ void k_bbase(const int* __restrict__ bcur, int* __restrict__ bbase) {
    __shared__ int sh[256];
    int t = threadIdx.x;
    int tot = 0;
    if (t < NB) {
        int dN = (NN - t * BW < BW) ? (NN - t * BW) : BW;
        tot = (bcur[t] - t * CAP) + dN;
    }
    sh[t] = tot;
    __syncthreads();
    for (int o = 1; o < 256; o <<= 1) {
        int add = (t >= o) ? sh[t - o] : 0;
        __syncthreads();
        sh[t] += add;
        __syncthreads();
    }
    if (t < NB) bbase[t] = sh[t] - tot;
}

// ------- split W1 (bf16 hi/lo, [n][k]) + W2 (f16 hi/lo, padded [48][256]) --
__global__ void k_splitW(const float* __restrict__ W1, ushort_t* __restrict__ W1ht,
                         ushort_t* __restrict__ W1lt, const float* __restrict__ W2,
                         ushort_t* __restrict__ W2ht, ushort_t* __restrict__ W2lt) {
    if (blockIdx.x < 256) {
        int k = blockIdx.x, n = threadIdx.x;
        float v = W1[k * 256 + n];
        ushort_t hi = f2bf(v);
        ushort_t lo = f2bf(v - bf2f(hi));
        W1ht[n * 256 + k] = hi;
        W1lt[n * 256 + k] = lo;
    } else {
        int n = blockIdx.x - 256, k = threadIdx.x;
        float v = (n < NCLS) ? W2[k * NCLS + n] : 0.f;
        ushort_t hi = f2h(v);
        ushort_t lo = f2h(v - h2f(hi));
        W2ht[n * 256 + k] = hi;
        W2lt[n * 256 + k] = lo;
    }
}

// ------ FUSED: GEMM1 (blocks < GB1) + CSR place (blocks >= GB1) ------------
#define LSTR 40   // ushorts per LDS row
__global__ __launch_bounds__(256) void k_gemm1s(const float* __restrict__ A,
                                                const ushort_t* __restrict__ Bht,
                                                const ushort_t* __restrict__ Blt,
                                                const float* __restrict__ attS,
                                                const float* __restrict__ attD,
                                                ushort_t* __restrict__ h1h,
                                                float* __restrict__ as1,
                                                float* __restrict__ ad1,
                                                const int* __restrict__ bcur,
                                                const int* __restrict__ bbase,
                                                const uint2* __restrict__ ebuf,
                                                int* __restrict__ offset,
                                                int* __restrict__ degt,
                                                int* __restrict__ csr_src) {
    __shared__ ushort_t Ah[128 * LSTR];
    __shared__ ushort_t Al[128 * LSTR];
    __shared__ ushort_t Bh[128 * LSTR];
    __shared__ ushort_t Bl[128 * LSTR];

    if (blockIdx.x >= GB1) {
        // ---------------- place body: derive offsets + scatter locally -----
        int b = blockIdx.x - GB1;
        int* cnt  = (int*)Ah;
        int* sA   = (int*)Al;
        int* sB   = (int*)Bh;
        int* lcur = (int*)Bl;
        int t = threadIdx.x;
        int d0 = b * BW;
        int dN = (NN - d0 < BW) ? (NN - d0) : BW;
        cnt[t] = (t < dN) ? 1 : 0;
        cnt[t + 256] = (t + 256 < dN) ? 1 : 0;
        __syncthreads();
        int bcurv = bcur[b];
        for (int i = b * CAP + t; i < bcurv; i += 256)
            atomicAdd(&cnt[ebuf[i].y - d0], 1);
        __syncthreads();
        int o0 = cnt[t], o1 = cnt[t + 256];
        sA[t] = o0; sA[t + 256] = o1;
        __syncthreads();
        int* sp = sA; int* dp = sB;
        for (int o = 1; o < 512; o <<= 1) {
            dp[t] = sp[t] + ((t >= o) ? sp[t - o] : 0);
            int t2 = t + 256;
            dp[t2] = sp[t2] + ((t2 >= o) ? sp[t2 - o] : 0);
            __syncthreads();
            int* tmp = sp; sp = dp; dp = tmp;
        }
        int base = bbase[b];
        if (t < dN) {
            int off = base + sp[t] - o0;
            offset[d0 + t] = off;
            degt[d0 + t] = o0;
            csr_src[off] = d0 + t;   // self loop
            lcur[t] = off + 1;
        }
        int t2 = t + 256;
        if (t2 < dN) {
            int off = base + sp[t2] - o1;
            offset[d0 + t2] = off;
            degt[d0 + t2] = o1;
            csr_src[off] = d0 + t2;
            lcur[t2] = off + 1;
        }
        __syncthreads();
        for (int i = b * CAP + t; i < bcurv; i += 256) {
            uint2 e = ebuf[i];
            int pos = atomicAdd(&lcur[e.y - d0], 1);
            csr_src[pos] = (int)e.x;
        }
        return;
    }

    // ---------------- GEMM body ----------------
    int bx = blockIdx.x & 1;
    int by = blockIdx.x >> 1;
    int row0 = by * 128, col0 = bx * 128;
    int t = threadIdx.x;
    int w = t >> 6, lane = t & 63;
    int lr = lane & 15, lg = lane >> 4;
    int R0 = (w >> 1) * 64, C0 = (w & 1) * 64;

    int ar = t >> 1, ah = t & 1;
    int gr_a = row0 + ar;

    f32x4 acc[4][4];
#pragma unroll
    for (int i = 0; i < 4; i++)
#pragma unroll
        for (int j = 0; j < 4; j++) acc[i][j] = (f32x4){0.f, 0.f, 0.f, 0.f};

    for (int it = 0; it < 8; it++) {
        int k0 = it * 32;
        __syncthreads();
        {
            float f[16];
            if (gr_a < NN) {
                const float* ap = A + (size_t)gr_a * 256 + k0 + ah * 16;
#pragma unroll
                for (int i = 0; i < 4; i++) {
                    float4 v = *reinterpret_cast<const float4*>(ap + i * 4);
                    f[i * 4 + 0] = v.x; f[i * 4 + 1] = v.y; f[i * 4 + 2] = v.z; f[i * 4 + 3] = v.w;
                }
            } else {
#pragma unroll
                for (int i = 0; i < 16; i++) f[i] = 0.f;
            }
            unsigned hw[8], lw[8];
#pragma unroll
            for (int i = 0; i < 8; i++) {
                ushort_t h0 = f2bf(f[2 * i]), h1v = f2bf(f[2 * i + 1]);
                ushort_t l0 = f2bf(f[2 * i] - bf2f(h0)), l1 = f2bf(f[2 * i + 1] - bf2f(h1v));
                hw[i] = (unsigned)h0 | ((unsigned)h1v << 16);
                lw[i] = (unsigned)l0 | ((unsigned)l1 << 16);
            }
            uint4* dsth = reinterpret_cast<uint4*>(&Ah[ar * LSTR + ah * 16]);
            dsth[0] = make_uint4(hw[0], hw[1], hw[2], hw[3]);
            dsth[1] = make_uint4(hw[4], hw[5], hw[6], hw[7]);
            uint4* dstl = reinterpret_cast<uint4*>(&Al[ar * LSTR + ah * 16]);
            dstl[0] = make_uint4(lw[0], lw[1], lw[2], lw[3]);
            dstl[1] = make_uint4(lw[4], lw[5], lw[6], lw[7]);
        }
        {
            int bn = t >> 1, bh2 = t & 1;
            const uint4* sh = reinterpret_cast<const uint4*>(Bht + (size_t)(col0 + bn) * 256 + k0 + bh2 * 16);
            const uint4* sl = reinterpret_cast<const uint4*>(Blt + (size_t)(col0 + bn) * 256 + k0 + bh2 * 16);
            uint4* dh = reinterpret_cast<uint4*>(&Bh[bn * LSTR + bh2 * 16]);
            uint4* dl = reinterpret_cast<uint4*>(&Bl[bn * LSTR + bh2 * 16]);
            dh[0] = sh[0]; dh[1] = sh[1];
            dl[0] = sl[0]; dl[1] = sl[1];
        }
        __syncthreads();
        short8 bhf[4], blf[4];
#pragma unroll
        for (int ni = 0; ni < 4; ni++) {
            int c = C0 + ni * 16 + lr;
            bhf[ni] = *reinterpret_cast<const short8*>(&Bh[c * LSTR + lg * 8]);
            blf[ni] = *reinterpret_cast<const short8*>(&Bl[c * LSTR + lg * 8]);
        }
#pragma unroll
        for (int mi = 0; mi < 4; mi++) {
            int r = R0 + mi * 16 + lr;
            short8 ahf = *reinterpret_cast<const short8*>(&Ah[r * LSTR + lg * 8]);
            short8 alf = *reinterpret_cast<const short8*>(&Al[r * LSTR + lg * 8]);
#pragma unroll
            for (int ni = 0; ni < 4; ni++) {
                acc[mi][ni] = __builtin_amdgcn_mfma_f32_16x16x32_bf16(ahf, bhf[ni], acc[mi][ni], 0, 0, 0);
                acc[mi][ni] = __builtin_amdgcn_mfma_f32_16x16x32_bf16(alf, bhf[ni], acc[mi][ni], 0, 0, 0);
                acc[mi][ni] = __builtin_amdgcn_mfma_f32_16x16x32_bf16(ahf, blf[ni], acc[mi][ni], 0, 0, 0);
            }
        }
    }

    int cn[4];
    float sa[4], da[4];
#pragma unroll
    for (int ni = 0; ni < 4; ni++) {
        cn[ni] = col0 + C0 + ni * 16 + lr;
        sa[ni] = attS[cn[ni]];
        da[ni] = attD[cn[ni]];
    }
    int head0 = (col0 + C0) >> 5;
#pragma unroll
    for (int mi = 0; mi < 4; mi++) {
#pragma unroll
        for (int r = 0; r < 4; r++) {
            int gr = row0 + R0 + mi * 16 + lg * 4 + r;
            float v0 = acc[mi][0][r], v1 = acc[mi][1][r];
            float v2 = acc[mi][2][r], v3 = acc[mi][3][r];
            float ps0 = v0 * sa[0] + v1 * sa[1];
            float pd0 = v0 * da[0] + v1 * da[1];
            float ps1 = v2 * sa[2] + v3 * sa[3];
            float pd1 = v2 * da[2] + v3 * da[3];
#pragma unroll
            for (int m = 1; m <= 8; m <<= 1) {
                ps0 += __shfl_xor(ps0, m);
                pd0 += __shfl_xor(pd0, m);
                ps1 += __shfl_xor(ps1, m);
                pd1 += __shfl_xor(pd1, m);
            }
            if (gr < NN) {
                if (lr == 0) {
                    as1[gr * 8 + head0] = ps0;
                    ad1[gr * 8 + head0] = pd0;
                    as1[gr * 8 + head0 + 1] = ps1;
                    ad1[gr * 8 + head0 + 1] = pd1;
                }
                ushort_t* hp = h1h + (size_t)gr * 256;
                hp[cn[0]] = f2h(v0);
                hp[cn[1]] = f2h(v1);
                hp[cn[2]] = f2h(v2);
                hp[cn[3]] = f2h(v3);
            }
        }
    }
}

// ------- MERGED softmax + aggregate, layer 1: one wave/node ----------------
// phase 1: stats in sub(3b) x head(3b) layout; phase 2: R12 agg loop with
// inline weight (f32).  Stats remapped via shfl from lane (lane>>3).
__global__ __launch_bounds__(256) void k_sa1(const int* __restrict__ csr_src,
                                             const int* __restrict__ offset,
                                             const int* __restrict__ degt,
                                             const ushort_t* __restrict__ h1h,
                                             const float* __restrict__ as1,
                                             const float* __restrict__ ad1,
                                             const float* __restrict__ bias1,
                                             ushort_t* __restrict__ h2h) {
    int wave = (blockIdx.x * blockDim.x + threadIdx.x) >> 6;
    int lane = threadIdx.x & 63;
    if (wave >= NN) return;
    int d = wave;
    int beg = offset[d], cnt = degt[d];
    // ---- phase 1: softmax stats ----
    int sub = lane >> 3, h = lane & 7;
    float ad = ad1[d * 8 + h];
    float m = -1e30f, s = 0.f;
    for (int j = sub; j < cnt; j += 8) {
        int src = csr_src[beg + j];
        float e = as1[src * 8 + h] + ad;
        e = (e > 0.f) ? e : SLOPE * e;
        float mn = fmaxf(m, e);
        s = s * __expf(m - mn) + __expf(e - mn);
        m = mn;
    }
#pragma unroll
    for (int mask = 8; mask <= 32; mask <<= 1) {
        float mo = __shfl_xor(m, mask);
        float so = __shfl_xor(s, mask);
        float mn = fmaxf(m, mo);
        s = s * __expf(m - mn) + so * __expf(mo - mn);
        m = mn;
    }
    float di = 1.f / (s + 1e-16f);
    // ---- remap stats to aggregate layout (head = lane>>3) ----
    int h2 = lane >> 3;
    float mh  = __shfl(m, h2);
    float dih = __shfl(di, h2);
    float adh = __shfl(ad, h2);
    // ---- phase 2: weighted aggregate ----
    int f0 = lane * 4;
    float ax = 0.f, ay = 0.f, az = 0.f, aw = 0.f;
#pragma unroll 4
    for (int j = 0; j < cnt; j++) {
        int src = csr_src[beg + j];
        float e = as1[src * 8 + h2] + adh;
        e = (e > 0.f) ? e : SLOPE * e;
        float p = __expf(e - mh) * dih;
        ushort4 hv = *reinterpret_cast<const ushort4*>(h1h + (size_t)src * 256 + f0);
        ax += p * (float)__builtin_bit_cast(_Float16, hv.x);
        ay += p * (float)__builtin_bit_cast(_Float16, hv.y);
        az += p * (float)__builtin_bit_cast(_Float16, hv.z);
        aw += p * (float)__builtin_bit_cast(_Float16, hv.w);
    }
    float4 b = *reinterpret_cast<const float4*>(bias1 + f0);
    float vx = ax + b.x;
    float vy = ay + b.y;
    float vz = az + b.z;
    float vw = aw + b.w;
    vx = (vx > 0.f) ? vx : expm1f(vx);
    vy = (vy > 0.f) ? vy : expm1f(vy);
    vz = (vz > 0.f) ? vz : expm1f(vz);
    vw = (vw > 0.f) ? vw : expm1f(vw);
    ushort4 o;
    o.x = f2h(vx); o.y = f2h(vy); o.z = f2h(vz); o.w = f2h(vw);
    *reinterpret_cast<ushort4*>(h2h + (size_t)d * 256 + f0) = o;
}

// ----------------- GEMM2 (MFMA f16): hh(f16) = h2h @ W2; fused alpha2 ------
__global__ __launch_bounds__(256) void k_gemm2(const ushort_t* __restrict__ A,
                                               const ushort_t* __restrict__ Bht,
                                               const ushort_t* __restrict__ Blt,
                                               const float* __restrict__ attS,
                                               const float* __restrict__ attD,
                                               ushort_t* __restrict__ hh,
                                               float* __restrict__ as2,
                                               float* __restrict__ ad2) {
    __shared__ ushort_t Ash[128 * LSTR];
    __shared__ ushort_t Bh[48 * LSTR];
    __shared__ ushort_t Bl[48 * LSTR];
    int row0 = blockIdx.x * 128;
    int t = threadIdx.x;
    int w = t >> 6, lane = t & 63;
    int lr = lane & 15, lg = lane >> 4;
    int R0 = w * 32;

    f32x4 acc[2][3];
#pragma unroll
    for (int i = 0; i < 2; i++)
#pragma unroll
        for (int j = 0; j < 3; j++) acc[i][j] = (f32x4){0.f, 0.f, 0.f, 0.f};

    for (int it = 0; it < 8; it++) {
        int k0 = it * 32;
        __syncthreads();
#pragma unroll
        for (int i = 0; i < 2; i++) {
            int chunk = t + i * 256;
            int r = chunk >> 2, part = chunk & 3;
            int gr = row0 + r;
            uint4 v = make_uint4(0u, 0u, 0u, 0u);
            if (gr < NN) v = *reinterpret_cast<const uint4*>(A + (size_t)gr * 256 + k0 + part * 8);
            *reinterpret_cast<uint4*>(&Ash[r * LSTR + part * 8]) = v;
        }
        if (t < 192) {
            int bn = t >> 2, part = t & 3;
            *reinterpret_cast<uint4*>(&Bh[bn * LSTR + part * 8]) =
                *reinterpret_cast<const uint4*>(Bht + (size_t)bn * 256 + k0 + part * 8);
            *reinterpret_cast<uint4*>(&Bl[bn * LSTR + part * 8]) =
                *reinterpret_cast<const uint4*>(Blt + (size_t)bn * 256 + k0 + part * 8);
        }
        __syncthreads();
        half8 bhf[3], blf[3];
#pragma unroll
        for (int ni = 0; ni < 3; ni++) {
            int c = ni * 16 + lr;
            bhf[ni] = *reinterpret_cast<const half8*>(&Bh[c * LSTR + lg * 8]);
            blf[ni] = *reinterpret_cast<const half8*>(&Bl[c * LSTR + lg * 8]);
        }
#pragma unroll
        for (int mi = 0; mi < 2; mi++) {
            int r = R0 + mi * 16 + lr;
            half8 af = *reinterpret_cast<const half8*>(&Ash[r * LSTR + lg * 8]);
#pragma unroll
            for (int ni = 0; ni < 3; ni++) {
                acc[mi][ni] = __builtin_amdgcn_mfma_f32_16x16x32_f16(af, bhf[ni], acc[mi][ni], 0, 0, 0);
                acc[mi][ni] = __builtin_amdgcn_mfma_f32_16x16x32_f16(af, blf[ni], acc[mi][ni], 0, 0, 0);
            }
        }
    }

    int cn[3];
    float sa[3], da[3];
#pragma unroll
    for (int ni = 0; ni < 3; ni++) {
        cn[ni] = ni * 16 + lr;
        sa[ni] = (cn[ni] < NCLS) ? attS[cn[ni]] : 0.f;
        da[ni] = (cn[ni] < NCLS) ? attD[cn[ni]] : 0.f;
    }
#pragma unroll
    for (int mi = 0; mi < 2; mi++) {
#pragma unroll
        for (int r = 0; r < 4; r++) {
            int gr = row0 + R0 + mi * 16 + lg * 4 + r;
            float v0 = acc[mi][0][r], v1 = acc[mi][1][r], v2 = acc[mi][2][r];
            float ps = v0 * sa[0] + v1 * sa[1] + v2 * sa[2];
            float pd = v0 * da[0] + v1 * da[1] + v2 * da[2];
#pragma unroll
            for (int m = 1; m <= 8; m <<= 1) {
                ps += __shfl_xor(ps, m);
                pd += __shfl_xor(pd, m);
            }
            if (gr < NN) {
                if (lr == 0) { as2[gr] = ps; ad2[gr] = pd; }
                ushort_t* hp = hh + (size_t)gr * NCLS;
                if (cn[0] < NCLS) hp[cn[0]] = f2h(v0);
                if (cn[1] < NCLS) hp[cn[1]] = f2h(v1);
                if (cn[2] < NCLS) hp[cn[2]] = f2h(v2);
            }
        }
    }
}

// ------- merged softmax + aggregate, layer 2: one wave/node ----------------
__global__ __launch_bounds__(256) void k_sa2(const int* __restrict__ csr_src,
                                             const int* __restrict__ offset,
                                             const int* __restrict__ degt,
                                             const ushort_t* __restrict__ hh,
                                             const float* __restrict__ as2,
                                             const float* __restrict__ ad2,
                                             const float* __restrict__ bias2,
                                             float* __restrict__ out) {
    int wave = (blockIdx.x * blockDim.x + threadIdx.x) >> 6;
    int lane = threadIdx.x & 63;
    if (wave >= NN) return;
    int d = wave;
    float ad = ad2[d];
    int beg = offset[d], cnt = degt[d];
    float m = -1e30f, s = 0.f;
    for (int j = lane; j < cnt; j += 64) {
        int src = csr_src[beg + j];
        float e = as2[src] + ad;
        e = (e > 0.f) ? e : SLOPE * e;
        float mn = fmaxf(m, e);
        s = s * __expf(m - mn) + __expf(e - mn);
        m = mn;
    }
#pragma unroll
    for (int mask = 1; mask <= 32; mask <<= 1) {
        float mo = __shfl_xor(m, mask);
        float so = __shfl_xor(s, mask);
        float mn = fmaxf(m, mo);
        s = s * __expf(m - mn) + so * __expf(mo - mn);
        m = mn;
    }
    float di = 1.f / (s + 1e-16f);
    int es = lane / 20;
    int ch = lane % 20;
    float a0 = 0.f, a1 = 0.f;
    for (int j0 = 0; j0 < cnt; j0 += 3) {
        int j = j0 + es;
        if (es < 3 && j < cnt) {
            int src = csr_src[beg + j];
            float e = as2[src] + ad;
            e = (e > 0.f) ? e : SLOPE * e;
            float w = __expf(e - m) * di;
            unsigned v = *reinterpret_cast<const unsigned*>(hh + (size_t)src * NCLS + ch * 2);
            a0 += w * (float)__builtin_bit_cast(_Float16, (ushort_t)(v & 0xFFFFu));
            a1 += w * (float)__builtin_bit_cast(_Float16, (ushort_t)(v >> 16));
        }
    }
    float t0 = __shfl(a0, lane + 20);
    float t1 = __shfl(a0, lane + 40);
    float u0 = __shfl(a1, lane + 20);
    float u1 = __shfl(a1, lane + 40);
    if (lane < 20) {
        float2 o;
        o.x = a0 + t0 + t1 + bias2[ch * 2];
        o.y = a1 + u0 + u1 + bias2[ch * 2 + 1];
        *reinterpret_cast<float2*>(out + (size_t)d * NCLS + ch * 2) = o;
    }
}

extern "C" void kernel_launch(void* const* d_in, const int* in_sizes, int n_in,
                              void* d_out, int out_size, void* d_ws, size_t ws_size,
                              hipStream_t stream) {
    const float* x      = (const float*)d_in[0];
    const int* ei       = (const int*)d_in[1];   // int64 in ref -> int32 on device
    const float* W1     = (const float*)d_in[2];
    const float* att_s1 = (const float*)d_in[3];
    const float* att_d1 = (const float*)d_in[4];
    const float* bias1  = (const float*)d_in[5];
    const float* W2     = (const float*)d_in[6];
    const float* att_s2 = (const float*)d_in[7];
    const float* att_d2 = (const float*)d_in[8];
    const float* bias2  = (const float*)d_in[9];
    float* out = (float*)d_out;

    char* ws = (char*)d_ws;
    size_t off = 0;
    auto alloc = [&](size_t bytes) -> void* {
        void* p = ws + off;
        off = (off + bytes + 255) & ~(size_t)255;
        return p;
    };
    ushort_t* h1h = (ushort_t*)alloc((size_t)NN * 256 * 2);
    ushort_t* h2h = (ushort_t*)alloc((size_t)NN * 256 * 2);
    ushort_t* hh  = (ushort_t*)alloc((size_t)NN * NCLS * 2);
    float* as1  = (float*)alloc((size_t)NN * 8 * 4);
    float* ad1  = (float*)alloc((size_t)NN * 8 * 4);
    float* as2  = (float*)alloc((size_t)NN * 4);
    float* ad2  = (float*)alloc((size_t)NN * 4);
    int* degt   = (int*)alloc((size_t)NN * 4);
    int* offs   = (int*)alloc((size_t)(NN + 1) * 4);
    int* csr    = (int*)alloc((size_t)ETOT * 4);
    uint2* ebuf = (uint2*)alloc((size_t)NB * CAP * 8);
    int* bcur   = (int*)alloc((size_t)NB * 4 + 256);
    int* bbase  = (int*)alloc((size_t)NB * 4 + 256);
    ushort_t* W1ht = (ushort_t*)alloc((size_t)256 * 256 * 2);
    ushort_t* W1lt = (ushort_t*)alloc((size_t)256 * 256 * 2);
    ushort_t* W2ht = (ushort_t*)alloc((size_t)48 * 256 * 2);
    ushort_t* W2lt = (ushort_t*)alloc((size_t)48 * 256 * 2);

    // CSR build (sort-free): bucket -> base-scan -> place (fused with gemm1)
    k_initbcur<<<1, 256, 0, stream>>>(bcur);
    k_bucket2<<<NBB, 256, 0, stream>>>(ei, bcur, ebuf);
    k_bbase<<<1, 256, 0, stream>>>(bcur, bbase);

    // Layer 1
    k_splitW<<<304, 256, 0, stream>>>(W1, W1ht, W1lt, W2, W2ht, W2lt);
    k_gemm1s<<<GB1 + NB, 256, 0, stream>>>(x, W1ht, W1lt, att_s1, att_d1, h1h, as1, ad1,
                                           bcur, bbase, ebuf, offs, degt, csr);
    k_sa1<<<(NN + 3) / 4, 256, 0, stream>>>(csr, offs, degt, h1h, as1, ad1, bias1, h2h);

    // Layer 2
    k_gemm2<<<(NN + 127) / 128, 256, 0, stream>>>(h2h, W2ht, W2lt, att_s2, att_d2, hh, as2, ad2);
    k_sa2<<<(NN + 3) / 4, 256, 0, stream>>>(csr, offs, degt, hh, as2, ad2, bias2, out);
}

// Round 16
// 375.308 us; speedup vs baseline: 2.3823x; 1.0379x over previous
//
#include <hip/hip_runtime.h>
#include <math.h>

#define NN 100000
#define NE 1600000
#define ETOT (NE + NN)
#define HEADS 8
#define NCLS 40
#define SLOPE 0.2f

#define BW 512                    // dsts per bucket
#define NB ((NN + BW - 1) / BW)   // 196 buckets
#define EPB 8192                  // edges per bucket-pass block
#define NBB ((NE + EPB - 1) / EPB) // 196
#define CAP 10240                 // ebuf capacity per bucket
#define GB1 (((NN + 127) / 128) * 2)  // 1564 gemm1 blocks

typedef unsigned short ushort_t;
typedef __attribute__((ext_vector_type(8))) short short8;
typedef __attribute__((ext_vector_type(8))) _Float16 half8;
typedef __attribute__((ext_vector_type(4))) float f32x4;

static __device__ __forceinline__ ushort_t f2bf(float f) {
    unsigned u = __float_as_uint(f);
    unsigned r = (u + 0x7FFFu + ((u >> 16) & 1u)) >> 16;   // RNE
    return (ushort_t)r;
}
static __device__ __forceinline__ float bf2f(ushort_t b) {
    return __uint_as_float(((unsigned)b) << 16);
}
static __device__ __forceinline__ ushort_t f2h(float f) {
    _Float16 h = (_Float16)f;
    return __builtin_bit_cast(ushort_t, h);
}
static __device__ __forceinline__ float h2f(ushort_t u) {
    return (float)__builtin_bit_cast(_Float16, u);
}

// ---- splitW (W1 bf16 hi/lo [n][k]; W2 f16 hi/lo padded [48][256]) + initbcur
__global__ void k_splitW(const float* __restrict__ W1, ushort_t* __restrict__ W1ht,
                         ushort_t* __restrict__ W1lt, const float* __restrict__ W2,
                         ushort_t* __restrict__ W2ht, ushort_t* __restrict__ W2lt,
                         int* __restrict__ bcur) {
    if (blockIdx.x < 256) {
        int k = blockIdx.x, n = threadIdx.x;
        float v = W1[k * 256 + n];
        ushort_t hi = f2bf(v);
        ushort_t lo = f2bf(v - bf2f(hi));
        W1ht[n * 256 + k] = hi;
        W1lt[n * 256 + k] = lo;
    } else if (blockIdx.x < 304) {
        int n = blockIdx.x - 256, k = threadIdx.x;
        float v = (n < NCLS) ? W2[k * NCLS + n] : 0.f;
        ushort_t hi = f2h(v);
        ushort_t lo = f2h(v - h2f(hi));
        W2ht[n * 256 + k] = hi;
        W2lt[n * 256 + k] = lo;
    } else {
        int b = threadIdx.x;
        if (b < NB) bcur[b] = b * CAP;
    }
}

// ------ FUSED: bucket partition (blocks < NBB) + GEMM1 (blocks >= NBB) -----
#define LSTR 40   // ushorts per LDS row
__global__ __launch_bounds__(256) void k_g1b(const float* __restrict__ A,
                                             const ushort_t* __restrict__ Bht,
                                             const ushort_t* __restrict__ Blt,
                                             const float* __restrict__ attS,
                                             const float* __restrict__ attD,
                                             ushort_t* __restrict__ h1h,
                                             float* __restrict__ as1,
                                             float* __restrict__ ad1,
                                             const int* __restrict__ ei,
                                             int* __restrict__ bcur,
                                             uint2* __restrict__ ebuf) {
    __shared__ ushort_t Ah[128 * LSTR];
    __shared__ ushort_t Al[128 * LSTR];
    __shared__ ushort_t Bh[128 * LSTR];
    __shared__ ushort_t Bl[128 * LSTR];

    if (blockIdx.x < NBB) {
        // ---------------- bucket body ----------------
        int* cnt  = (int*)Ah;
        int* cnt2 = (int*)Al;
        int* base = (int*)Bh;
        int t = threadIdx.x;
        for (int b = t; b < NB; b += 256) { cnt[b] = 0; cnt2[b] = 0; }
        __syncthreads();
        int e0 = blockIdx.x * EPB;
#pragma unroll 4
        for (int i = 0; i < EPB / 256; i++) {
            int e = e0 + i * 256 + t;
            if (e < NE) {
                unsigned d = (unsigned)ei[NE + e];
                unsigned s = (unsigned)ei[e];
                if (d < NN && s < NN) atomicAdd(&cnt[d >> 9], 1);
            }
        }
        __syncthreads();
        for (int b = t; b < NB; b += 256) {
            base[b] = cnt[b] ? atomicAdd(&bcur[b], cnt[b]) : 0;
        }
        __syncthreads();
#pragma unroll 4
        for (int i = 0; i < EPB / 256; i++) {
            int e = e0 + i * 256 + t;
            if (e < NE) {
                unsigned d = (unsigned)ei[NE + e];
                unsigned s = (unsigned)ei[e];
                if (d < NN && s < NN) {
                    int b = d >> 9;
                    int r = atomicAdd(&cnt2[b], 1);
                    ebuf[base[b] + r] = make_uint2(s, d);
                }
            }
        }
        return;
    }

    // ---------------- GEMM body ----------------
    int bid = blockIdx.x - NBB;
    int bx = bid & 1;
    int by = bid >> 1;
    int row0 = by * 128, col0 = bx * 128;
    int t = threadIdx.x;
    int w = t >> 6, lane = t & 63;
    int lr = lane & 15, lg = lane >> 4;
    int R0 = (w >> 1) * 64, C0 = (w & 1) * 64;

    int ar = t >> 1, ah = t & 1;
    int gr_a = row0 + ar;

    f32x4 acc[4][4];
#pragma unroll
    for (int i = 0; i < 4; i++)
#pragma unroll
        for (int j = 0; j < 4; j++) acc[i][j] = (f32x4){0.f, 0.f, 0.f, 0.f};

    for (int it = 0; it < 8; it++) {
        int k0 = it * 32;
        __syncthreads();
        {
            float f[16];
            if (gr_a < NN) {
                const float* ap = A + (size_t)gr_a * 256 + k0 + ah * 16;
#pragma unroll
                for (int i = 0; i < 4; i++) {
                    float4 v = *reinterpret_cast<const float4*>(ap + i * 4);
                    f[i * 4 + 0] = v.x; f[i * 4 + 1] = v.y; f[i * 4 + 2] = v.z; f[i * 4 + 3] = v.w;
                }
            } else {
#pragma unroll
                for (int i = 0; i < 16; i++) f[i] = 0.f;
            }
            unsigned hw[8], lw[8];
#pragma unroll
            for (int i = 0; i < 8; i++) {
                ushort_t h0 = f2bf(f[2 * i]), h1v = f2bf(f[2 * i + 1]);
                ushort_t l0 = f2bf(f[2 * i] - bf2f(h0)), l1 = f2bf(f[2 * i + 1] - bf2f(h1v));
                hw[i] = (unsigned)h0 | ((unsigned)h1v << 16);
                lw[i] = (unsigned)l0 | ((unsigned)l1 << 16);
            }
            uint4* dsth = reinterpret_cast<uint4*>(&Ah[ar * LSTR + ah * 16]);
            dsth[0] = make_uint4(hw[0], hw[1], hw[2], hw[3]);
            dsth[1] = make_uint4(hw[4], hw[5], hw[6], hw[7]);
            uint4* dstl = reinterpret_cast<uint4*>(&Al[ar * LSTR + ah * 16]);
            dstl[0] = make_uint4(lw[0], lw[1], lw[2], lw[3]);
            dstl[1] = make_uint4(lw[4], lw[5], lw[6], lw[7]);
        }
        {
            int bn = t >> 1, bh2 = t & 1;
            const uint4* sh = reinterpret_cast<const uint4*>(Bht + (size_t)(col0 + bn) * 256 + k0 + bh2 * 16);
            const uint4* sl = reinterpret_cast<const uint4*>(Blt + (size_t)(col0 + bn) * 256 + k0 + bh2 * 16);
            uint4* dh = reinterpret_cast<uint4*>(&Bh[bn * LSTR + bh2 * 16]);
            uint4* dl = reinterpret_cast<uint4*>(&Bl[bn * LSTR + bh2 * 16]);
            dh[0] = sh[0]; dh[1] = sh[1];
            dl[0] = sl[0]; dl[1] = sl[1];
        }
        __syncthreads();
        short8 bhf[4], blf[4];
#pragma unroll
        for (int ni = 0; ni < 4; ni++) {
            int c = C0 + ni * 16 + lr;
            bhf[ni] = *reinterpret_cast<const short8*>(&Bh[c * LSTR + lg * 8]);
            blf[ni] = *reinterpret_cast<const short8*>(&Bl[c * LSTR + lg * 8]);
        }
#pragma unroll
        for (int mi = 0; mi < 4; mi++) {
            int r = R0 + mi * 16 + lr;
            short8 ahf = *reinterpret_cast<const short8*>(&Ah[r * LSTR + lg * 8]);
            short8 alf = *reinterpret_cast<const short8*>(&Al[r * LSTR + lg * 8]);
#pragma unroll
            for (int ni = 0; ni < 4; ni++) {
                acc[mi][ni] = __builtin_amdgcn_mfma_f32_16x16x32_bf16(ahf, bhf[ni], acc[mi][ni], 0, 0, 0);
                acc[mi][ni] = __builtin_amdgcn_mfma_f32_16x16x32_bf16(alf, bhf[ni], acc[mi][ni], 0, 0, 0);
                acc[mi][ni] = __builtin_amdgcn_mfma_f32_16x16x32_bf16(ahf, blf[ni], acc[mi][ni], 0, 0, 0);
            }
        }
    }

    int cn[4];
    float sa[4], da[4];
#pragma unroll
    for (int ni = 0; ni < 4; ni++) {
        cn[ni] = col0 + C0 + ni * 16 + lr;
        sa[ni] = attS[cn[ni]];
        da[ni] = attD[cn[ni]];
    }
    int head0 = (col0 + C0) >> 5;
#pragma unroll
    for (int mi = 0; mi < 4; mi++) {
#pragma unroll
        for (int r = 0; r < 4; r++) {
            int gr = row0 + R0 + mi * 16 + lg * 4 + r;
            float v0 = acc[mi][0][r], v1 = acc[mi][1][r];
            float v2 = acc[mi][2][r], v3 = acc[mi][3][r];
            float ps0 = v0 * sa[0] + v1 * sa[1];
            float pd0 = v0 * da[0] + v1 * da[1];
            float ps1 = v2 * sa[2] + v3 * sa[3];
            float pd1 = v2 * da[2] + v3 * da[3];
#pragma unroll
            for (int m = 1; m <= 8; m <<= 1) {
                ps0 += __shfl_xor(ps0, m);
                pd0 += __shfl_xor(pd0, m);
                ps1 += __shfl_xor(ps1, m);
                pd1 += __shfl_xor(pd1, m);
            }
            if (gr < NN) {
                if (lr == 0) {
                    as1[gr * 8 + head0] = ps0;
                    ad1[gr * 8 + head0] = pd0;
                    as1[gr * 8 + head0 + 1] = ps1;
                    ad1[gr * 8 + head0 + 1] = pd1;
                }
                ushort_t* hp = h1h + (size_t)gr * 256;
                hp[cn[0]] = f2h(v0);
                hp[cn[1]] = f2h(v1);
                hp[cn[2]] = f2h(v2);
                hp[cn[3]] = f2h(v3);
            }
        }
    }
}

// ---- place: derive offsets/deg from bucket, scatter locally (inline bbase) -
__global__ __launch_bounds__(256) void k_place(const int* __restrict__ bcur,
                                               const uint2* __restrict__ ebuf,
                                               int* __restrict__ offset,
                                               int* __restrict__ degt,
                                               int* __restrict__ csr_src) {
    __shared__ int cnt[BW];
    __shared__ int sA[BW];
    __shared__ int sB[BW];
    __shared__ int lcur[BW];
    __shared__ int bsh[256];
    int b = blockIdx.x;
    int t = threadIdx.x;
    // inline bbase: exclusive prefix over bucket totals
    int tot = 0;
    if (t < NB) {
        int dNt = (NN - t * BW < BW) ? (NN - t * BW) : BW;
        tot = (bcur[t] - t * CAP) + dNt;
    }
    bsh[t] = tot;
    __syncthreads();
    for (int o = 1; o < 256; o <<= 1) {
        int add = (t >= o) ? bsh[t - o] : 0;
        __syncthreads();
        bsh[t] += add;
        __syncthreads();
    }
    int base = (b > 0) ? bsh[b - 1] : 0;

    int d0 = b * BW;
    int dN = (NN - d0 < BW) ? (NN - d0) : BW;
    cnt[t] = (t < dN) ? 1 : 0;
    cnt[t + 256] = (t + 256 < dN) ? 1 : 0;
    __syncthreads();
    int bcurv = bcur[b];
    for (int i = b * CAP + t; i < bcurv; i += 256)
        atomicAdd(&cnt[ebuf[i].y - d0], 1);
    __syncthreads();
    int o0 = cnt[t], o1 = cnt[t + 256];
    sA[t] = o0; sA[t + 256] = o1;
    __syncthreads();
    int* sp = sA; int* dp = sB;
    for (int o = 1; o < 512; o <<= 1) {
        dp[t] = sp[t] + ((t >= o) ? sp[t - o] : 0);
        int t2 = t + 256;
        dp[t2] = sp[t2] + ((t2 >= o) ? sp[t2 - o] : 0);
        __syncthreads();
        int* tmp = sp; sp = dp; dp = tmp;
    }
    if (t < dN) {
        int off = base + sp[t] - o0;
        offset[d0 + t] = off;
        degt[d0 + t] = o0;
        csr_src[off] = d0 + t;   // self loop
        lcur[t] = off + 1;
    }
    int t2 = t + 256;
    if (t2 < dN) {
        int off = base + sp[t2] - o1;
        offset[d0 + t2] = off;
        degt[d0 + t2] = o1;
        csr_src[off] = d0 + t2;
        lcur[t2] = off + 1;
    }
    __syncthreads();
    for (int i = b * CAP + t; i < bcurv; i += 256) {
        uint2 e = ebuf[i];
        int pos = atomicAdd(&lcur[e.y - d0], 1);
        csr_src[pos] = (int)e.x;
    }
}

// ------- MERGED softmax + aggregate, layer 1: one wave/node ----------------
__global__ __launch_bounds__(256) void k_sa1(const int* __restrict__ csr_src,
                                             const int* __restrict__ offset,
                                             const int* __restrict__ degt,
                                             const ushort_t* __restrict__ h1h,
                                             const float* __restrict__ as1,
                                             const float* __restrict__ ad1,
                                             const float* __restrict__ bias1,
                                             ushort_t* __restrict__ h2h) {
    int wave = (blockIdx.x * blockDim.x + threadIdx.x) >> 6;
    int lane = threadIdx.x & 63;
    if (wave >= NN) return;
    int d = wave;
    int beg = offset[d], cnt = degt[d];
    int sub = lane >> 3, h = lane & 7;
    float ad = ad1[d * 8 + h];
    float m = -1e30f, s = 0.f;
    for (int j = sub; j < cnt; j += 8) {
        int src = csr_src[beg + j];
        float e = as1[src * 8 + h] + ad;
        e = (e > 0.f) ? e : SLOPE * e;
        float mn = fmaxf(m, e);
        s = s * __expf(m - mn) + __expf(e - mn);
        m = mn;
    }
#pragma unroll
    for (int mask = 8; mask <= 32; mask <<= 1) {
        float mo = __shfl_xor(m, mask);
        float so = __shfl_xor(s, mask);
        float mn = fmaxf(m, mo);
        s = s * __expf(m - mn) + so * __expf(mo - mn);
        m = mn;
    }
    float di = 1.f / (s + 1e-16f);
    int h2 = lane >> 3;
    float mh  = __shfl(m, h2);
    float dih = __shfl(di, h2);
    float adh = __shfl(ad, h2);
    int f0 = lane * 4;
    float ax = 0.f, ay = 0.f, az = 0.f, aw = 0.f;
#pragma unroll 4
    for (int j = 0; j < cnt; j++) {
        int src = csr_src[beg + j];
        float e = as1[src * 8 + h2] + adh;
        e = (e > 0.f) ? e : SLOPE * e;
        float p = __expf(e - mh) * dih;
        ushort4 hv = *reinterpret_cast<const ushort4*>(h1h + (size_t)src * 256 + f0);
        ax += p * (float)__builtin_bit_cast(_Float16, hv.x);
        ay += p * (float)__builtin_bit_cast(_Float16, hv.y);
        az += p * (float)__builtin_bit_cast(_Float16, hv.z);
        aw += p * (float)__builtin_bit_cast(_Float16, hv.w);
    }
    float4 b = *reinterpret_cast<const float4*>(bias1 + f0);
    float vx = ax + b.x;
    float vy = ay + b.y;
    float vz = az + b.z;
    float vw = aw + b.w;
    vx = (vx > 0.f) ? vx : expm1f(vx);
    vy = (vy > 0.f) ? vy : expm1f(vy);
    vz = (vz > 0.f) ? vz : expm1f(vz);
    vw = (vw > 0.f) ? vw : expm1f(vw);
    ushort4 o;
    o.x = f2h(vx); o.y = f2h(vy); o.z = f2h(vz); o.w = f2h(vw);
    *reinterpret_cast<ushort4*>(h2h + (size_t)d * 256 + f0) = o;
}

// ----------------- GEMM2 (MFMA f16): hh(f16) = h2h @ W2; fused alpha2 ------
__global__ __launch_bounds__(256) void k_gemm2(const ushort_t* __restrict__ A,
                                               const ushort_t* __restrict__ Bht,
                                               const ushort_t* __restrict__ Blt,
                                               const float* __restrict__ attS,
                                               const float* __restrict__ attD,
                                               ushort_t* __restrict__ hh,
                                               float* __restrict__ as2,
                                               float* __restrict__ ad2) {
    __shared__ ushort_t Ash[128 * LSTR];
    __shared__ ushort_t Bh[48 * LSTR];
    __shared__ ushort_t Bl[48 * LSTR];
    int row0 = blockIdx.x * 128;
    int t = threadIdx.x;
    int w = t >> 6, lane = t & 63;
    int lr = lane & 15, lg = lane >> 4;
    int R0 = w * 32;

    f32x4 acc[2][3];
#pragma unroll
    for (int i = 0; i < 2; i++)
#pragma unroll
        for (int j = 0; j < 3; j++) acc[i][j] = (f32x4){0.f, 0.f, 0.f, 0.f};

    for (int it = 0; it < 8; it++) {
        int k0 = it * 32;
        __syncthreads();
#pragma unroll
        for (int i = 0; i < 2; i++) {
            int chunk = t + i * 256;
            int r = chunk >> 2, part = chunk & 3;
            int gr = row0 + r;
            uint4 v = make_uint4(0u, 0u, 0u, 0u);
            if (gr < NN) v = *reinterpret_cast<const uint4*>(A + (size_t)gr * 256 + k0 + part * 8);
            *reinterpret_cast<uint4*>(&Ash[r * LSTR + part * 8]) = v;
        }
        if (t < 192) {
            int bn = t >> 2, part = t & 3;
            *reinterpret_cast<uint4*>(&Bh[bn * LSTR + part * 8]) =
                *reinterpret_cast<const uint4*>(Bht + (size_t)bn * 256 + k0 + part * 8);
            *reinterpret_cast<uint4*>(&Bl[bn * LSTR + part * 8]) =
                *reinterpret_cast<const uint4*>(Blt + (size_t)bn * 256 + k0 + part * 8);
        }
        __syncthreads();
        half8 bhf[3], blf[3];
#pragma unroll
        for (int ni = 0; ni < 3; ni++) {
            int c = ni * 16 + lr;
            bhf[ni] = *reinterpret_cast<const half8*>(&Bh[c * LSTR + lg * 8]);
            blf[ni] = *reinterpret_cast<const half8*>(&Bl[c * LSTR + lg * 8]);
        }
#pragma unroll
        for (int mi = 0; mi < 2; mi++) {
            int r = R0 + mi * 16 + lr;
            half8 af = *reinterpret_cast<const half8*>(&Ash[r * LSTR + lg * 8]);
#pragma unroll
            for (int ni = 0; ni < 3; ni++) {
                acc[mi][ni] = __builtin_amdgcn_mfma_f32_16x16x32_f16(af, bhf[ni], acc[mi][ni], 0, 0, 0);
                acc[mi][ni] = __builtin_amdgcn_mfma_f32_16x16x32_f16(af, blf[ni], acc[mi][ni], 0, 0, 0);
            }
        }
    }

    int cn[3];
    float sa[3], da[3];
#pragma unroll
    for (int ni = 0; ni < 3; ni++) {
        cn[ni] = ni * 16 + lr;
        sa[ni] = (cn[ni] < NCLS) ? attS[cn[ni]] : 0.f;
        da[ni] = (cn[ni] < NCLS) ? attD[cn[ni]] : 0.f;
    }
#pragma unroll
    for (int mi = 0; mi < 2; mi++) {
#pragma unroll
        for (int r = 0; r < 4; r++) {
            int gr = row0 + R0 + mi * 16 + lg * 4 + r;
            float v0 = acc[mi][0][r], v1 = acc[mi][1][r], v2 = acc[mi][2][r];
            float ps = v0 * sa[0] + v1 * sa[1] + v2 * sa[2];
            float pd = v0 * da[0] + v1 * da[1] + v2 * da[2];
#pragma unroll
            for (int m = 1; m <= 8; m <<= 1) {
                ps += __shfl_xor(ps, m);
                pd += __shfl_xor(pd, m);
            }
            if (gr < NN) {
                if (lr == 0) { as2[gr] = ps; ad2[gr] = pd; }
                ushort_t* hp = hh + (size_t)gr * NCLS;
                if (cn[0] < NCLS) hp[cn[0]] = f2h(v0);
                if (cn[1] < NCLS) hp[cn[1]] = f2h(v1);
                if (cn[2] < NCLS) hp[cn[2]] = f2h(v2);
            }
        }
    }
}

// ------- merged softmax + aggregate, layer 2: one wave/node ----------------
__global__ __launch_bounds__(256) void k_sa2(const int* __restrict__ csr_src,
                                             const int* __restrict__ offset,
                                             const int* __restrict__ degt,
                                             const ushort_t* __restrict__ hh,
                                             const float* __restrict__ as2,
                                             const float* __restrict__ ad2,
                                             const float* __restrict__ bias2,
                                             float* __restrict__ out) {
    int wave = (blockIdx.x * blockDim.x + threadIdx.x) >> 6;
    int lane = threadIdx.x & 63;
    if (wave >= NN) return;
    int d = wave;
    float ad = ad2[d];
    int beg = offset[d], cnt = degt[d];
    float m = -1e30f, s = 0.f;
    for (int j = lane; j < cnt; j += 64) {
        int src = csr_src[beg + j];
        float e = as2[src] + ad;
        e = (e > 0.f) ? e : SLOPE * e;
        float mn = fmaxf(m, e);
        s = s * __expf(m - mn) + __expf(e - mn);
        m = mn;
    }
#pragma unroll
    for (int mask = 1; mask <= 32; mask <<= 1) {
        float mo = __shfl_xor(m, mask);
        float so = __shfl_xor(s, mask);
        float mn = fmaxf(m, mo);
        s = s * __expf(m - mn) + so * __expf(mo - mn);
        m = mn;
    }
    float di = 1.f / (s + 1e-16f);
    int es = lane / 20;
    int ch = lane % 20;
    float a0 = 0.f, a1 = 0.f;
    for (int j0 = 0; j0 < cnt; j0 += 3) {
        int j = j0 + es;
        if (es < 3 && j < cnt) {
            int src = csr_src[beg + j];
            float e = as2[src] + ad;
            e = (e > 0.f) ? e : SLOPE * e;
            float w = __expf(e - m) * di;
            unsigned v = *reinterpret_cast<const unsigned*>(hh + (size_t)src * NCLS + ch * 2);
            a0 += w * (float)__builtin_bit_cast(_Float16, (ushort_t)(v & 0xFFFFu));
            a1 += w * (float)__builtin_bit_cast(_Float16, (ushort_t)(v >> 16));
        }
    }
    float t0 = __shfl(a0, lane + 20);
    float t1 = __shfl(a0, lane + 40);
    float u0 = __shfl(a1, lane + 20);
    float u1 = __shfl(a1, lane + 40);
    if (lane < 20) {
        float2 o;
        o.x = a0 + t0 + t1 + bias2[ch * 2];
        o.y = a1 + u0 + u1 + bias2[ch * 2 + 1];
        *reinterpret_cast<float2*>(out + (size_t)d * NCLS + ch * 2) = o;
    }
}

extern "C" void kernel_launch(void* const* d_in, const int* in_sizes, int n_in,
                              void* d_out, int out_size, void* d_ws, size_t ws_size,
                              hipStream_t stream) {
    const float* x      = (const float*)d_in[0];
    const int* ei       = (const int*)d_in[1];   // int64 in ref -> int32 on device
    const float* W1     = (const float*)d_in[2];
    const float* att_s1 = (const float*)d_in[3];
    const float* att_d1 = (const float*)d_in[4];
    const float* bias1  = (const float*)d_in[5];
    const float* W2     = (const float*)d_in[6];
    const float* att_s2 = (const float*)d_in[7];
    const float* att_d2 = (const float*)d_in[8];
    const float* bias2  = (const float*)d_in[9];
    float* out = (float*)d_out;

    char* ws = (char*)d_ws;
    size_t off = 0;
    auto alloc = [&](size_t bytes) -> void* {
        void* p = ws + off;
        off = (off + bytes + 255) & ~(size_t)255;
        return p;
    };
    ushort_t* h1h = (ushort_t*)alloc((size_t)NN * 256 * 2);
    ushort_t* h2h = (ushort_t*)alloc((size_t)NN * 256 * 2);
    ushort_t* hh  = (ushort_t*)alloc((size_t)NN * NCLS * 2);
    float* as1  = (float*)alloc((size_t)NN * 8 * 4);
    float* ad1  = (float*)alloc((size_t)NN * 8 * 4);
    float* as2  = (float*)alloc((size_t)NN * 4);
    float* ad2  = (float*)alloc((size_t)NN * 4);
    int* degt   = (int*)alloc((size_t)NN * 4);
    int* offs   = (int*)alloc((size_t)(NN + 1) * 4);
    int* csr    = (int*)alloc((size_t)ETOT * 4);
    uint2* ebuf = (uint2*)alloc((size_t)NB * CAP * 8);
    int* bcur   = (int*)alloc((size_t)NB * 4 + 256);
    ushort_t* W1ht = (ushort_t*)alloc((size_t)256 * 256 * 2);
    ushort_t* W1lt = (ushort_t*)alloc((size_t)256 * 256 * 2);
    ushort_t* W2ht = (ushort_t*)alloc((size_t)48 * 256 * 2);
    ushort_t* W2lt = (ushort_t*)alloc((size_t)48 * 256 * 2);

    // 1) weight split + bucket-cursor init
    k_splitW<<<305, 256, 0, stream>>>(W1, W1ht, W1lt, W2, W2ht, W2lt, bcur);
    // 2) fused bucket partition + GEMM1
    k_g1b<<<NBB + GB1, 256, 0, stream>>>(x, W1ht, W1lt, att_s1, att_d1, h1h, as1, ad1,
                                         ei, bcur, ebuf);
    // 3) CSR place (inline bucket-base scan)
    k_place<<<NB, 256, 0, stream>>>(bcur, ebuf, offs, degt, csr);
    // 4) layer-1 softmax+aggregate
    k_sa1<<<(NN + 3) / 4, 256, 0, stream>>>(csr, offs, degt, h1h, as1, ad1, bias1, h2h);
    // 5) GEMM2 + alpha2
    k_gemm2<<<(NN + 127) / 128, 256, 0, stream>>>(h2h, W2ht, W2lt, att_s2, att_d2, hh, as2, ad2);
    // 6) layer-2 softmax+aggregate
    k_sa2<<<(NN + 3) / 4, 256, 0, stream>>>(csr, offs, degt, hh, as2, ad2, bias2, out);
}

// Round 17
// 370.413 us; speedup vs baseline: 2.4137x; 1.0132x over previous
//
#include <hip/hip_runtime.h>
#include <math.h>

#define NN 100000
#define NE 1600000
#define ETOT (NE + NN)
#define HEADS 8
#define NCLS 40
#define SLOPE 0.2f
#define ESHIFT 3.0f   // fixed softmax shift (logits bounded ~|2.5|; exp-safe)

#define BW 512                    // dsts per bucket
#define NB ((NN + BW - 1) / BW)   // 196 buckets
#define EPB 8192                  // edges per bucket-pass block
#define NBB ((NE + EPB - 1) / EPB) // 196
#define CAP 10240                 // ebuf capacity per bucket
#define GB1 (((NN + 127) / 128) * 2)  // 1564 gemm1 blocks

typedef unsigned short ushort_t;
typedef __attribute__((ext_vector_type(8))) short short8;
typedef __attribute__((ext_vector_type(8))) _Float16 half8;
typedef __attribute__((ext_vector_type(4))) float f32x4;

static __device__ __forceinline__ ushort_t f2bf(float f) {
    unsigned u = __float_as_uint(f);
    unsigned r = (u + 0x7FFFu + ((u >> 16) & 1u)) >> 16;   // RNE
    return (ushort_t)r;
}
static __device__ __forceinline__ float bf2f(ushort_t b) {
    return __uint_as_float(((unsigned)b) << 16);
}
static __device__ __forceinline__ ushort_t f2h(float f) {
    _Float16 h = (_Float16)f;
    return __builtin_bit_cast(ushort_t, h);
}
static __device__ __forceinline__ float h2f(ushort_t u) {
    return (float)__builtin_bit_cast(_Float16, u);
}

// ---- splitW (W1 bf16 hi/lo [n][k]; W2 f16 hi/lo padded [48][256]) + initbcur
__global__ void k_splitW(const float* __restrict__ W1, ushort_t* __restrict__ W1ht,
                         ushort_t* __restrict__ W1lt, const float* __restrict__ W2,
                         ushort_t* __restrict__ W2ht, ushort_t* __restrict__ W2lt,
                         int* __restrict__ bcur) {
    if (blockIdx.x < 256) {
        int k = blockIdx.x, n = threadIdx.x;
        float v = W1[k * 256 + n];
        ushort_t hi = f2bf(v);
        ushort_t lo = f2bf(v - bf2f(hi));
        W1ht[n * 256 + k] = hi;
        W1lt[n * 256 + k] = lo;
    } else if (blockIdx.x < 304) {
        int n = blockIdx.x - 256, k = threadIdx.x;
        float v = (n < NCLS) ? W2[k * NCLS + n] : 0.f;
        ushort_t hi = f2h(v);
        ushort_t lo = f2h(v - h2f(hi));
        W2ht[n * 256 + k] = hi;
        W2lt[n * 256 + k] = lo;
    } else {
        int b = threadIdx.x;
        if (b < NB) bcur[b] = b * CAP;
    }
}

// ------ FUSED: bucket partition (blocks < NBB) + GEMM1 (blocks >= NBB) -----
#define LSTR 40   // ushorts per LDS row
__global__ __launch_bounds__(256) void k_g1b(const float* __restrict__ A,
                                             const ushort_t* __restrict__ Bht,
                                             const ushort_t* __restrict__ Blt,
                                             const float* __restrict__ attS,
                                             const float* __restrict__ attD,
                                             ushort_t* __restrict__ h1h,
                                             float* __restrict__ as1,
                                             float* __restrict__ ad1,
                                             const int* __restrict__ ei,
                                             int* __restrict__ bcur,
                                             uint2* __restrict__ ebuf) {
    __shared__ ushort_t Ah[128 * LSTR];
    __shared__ ushort_t Al[128 * LSTR];
    __shared__ ushort_t Bh[128 * LSTR];
    __shared__ ushort_t Bl[128 * LSTR];

    if (blockIdx.x < NBB) {
        // ---------------- bucket body ----------------
        int* cnt  = (int*)Ah;
        int* cnt2 = (int*)Al;
        int* base = (int*)Bh;
        int t = threadIdx.x;
        for (int b = t; b < NB; b += 256) { cnt[b] = 0; cnt2[b] = 0; }
        __syncthreads();
        int e0 = blockIdx.x * EPB;
#pragma unroll 4
        for (int i = 0; i < EPB / 256; i++) {
            int e = e0 + i * 256 + t;
            if (e < NE) {
                unsigned d = (unsigned)ei[NE + e];
                unsigned s = (unsigned)ei[e];
                if (d < NN && s < NN) atomicAdd(&cnt[d >> 9], 1);
            }
        }
        __syncthreads();
        for (int b = t; b < NB; b += 256) {
            base[b] = cnt[b] ? atomicAdd(&bcur[b], cnt[b]) : 0;
        }
        __syncthreads();
#pragma unroll 4
        for (int i = 0; i < EPB / 256; i++) {
            int e = e0 + i * 256 + t;
            if (e < NE) {
                unsigned d = (unsigned)ei[NE + e];
                unsigned s = (unsigned)ei[e];
                if (d < NN && s < NN) {
                    int b = d >> 9;
                    int r = atomicAdd(&cnt2[b], 1);
                    ebuf[base[b] + r] = make_uint2(s, d);
                }
            }
        }
        return;
    }

    // ---------------- GEMM body ----------------
    int bid = blockIdx.x - NBB;
    int bx = bid & 1;
    int by = bid >> 1;
    int row0 = by * 128, col0 = bx * 128;
    int t = threadIdx.x;
    int w = t >> 6, lane = t & 63;
    int lr = lane & 15, lg = lane >> 4;
    int R0 = (w >> 1) * 64, C0 = (w & 1) * 64;

    int ar = t >> 1, ah = t & 1;
    int gr_a = row0 + ar;

    f32x4 acc[4][4];
#pragma unroll
    for (int i = 0; i < 4; i++)
#pragma unroll
        for (int j = 0; j < 4; j++) acc[i][j] = (f32x4){0.f, 0.f, 0.f, 0.f};

    for (int it = 0; it < 8; it++) {
        int k0 = it * 32;
        __syncthreads();
        {
            float f[16];
            if (gr_a < NN) {
                const float* ap = A + (size_t)gr_a * 256 + k0 + ah * 16;
#pragma unroll
                for (int i = 0; i < 4; i++) {
                    float4 v = *reinterpret_cast<const float4*>(ap + i * 4);
                    f[i * 4 + 0] = v.x; f[i * 4 + 1] = v.y; f[i * 4 + 2] = v.z; f[i * 4 + 3] = v.w;
                }
            } else {
#pragma unroll
                for (int i = 0; i < 16; i++) f[i] = 0.f;
            }
            unsigned hw[8], lw[8];
#pragma unroll
            for (int i = 0; i < 8; i++) {
                ushort_t h0 = f2bf(f[2 * i]), h1v = f2bf(f[2 * i + 1]);
                ushort_t l0 = f2bf(f[2 * i] - bf2f(h0)), l1 = f2bf(f[2 * i + 1] - bf2f(h1v));
                hw[i] = (unsigned)h0 | ((unsigned)h1v << 16);
                lw[i] = (unsigned)l0 | ((unsigned)l1 << 16);
            }
            uint4* dsth = reinterpret_cast<uint4*>(&Ah[ar * LSTR + ah * 16]);
            dsth[0] = make_uint4(hw[0], hw[1], hw[2], hw[3]);
            dsth[1] = make_uint4(hw[4], hw[5], hw[6], hw[7]);
            uint4* dstl = reinterpret_cast<uint4*>(&Al[ar * LSTR + ah * 16]);
            dstl[0] = make_uint4(lw[0], lw[1], lw[2], lw[3]);
            dstl[1] = make_uint4(lw[4], lw[5], lw[6], lw[7]);
        }
        {
            int bn = t >> 1, bh2 = t & 1;
            const uint4* sh = reinterpret_cast<const uint4*>(Bht + (size_t)(col0 + bn) * 256 + k0 + bh2 * 16);
            const uint4* sl = reinterpret_cast<const uint4*>(Blt + (size_t)(col0 + bn) * 256 + k0 + bh2 * 16);
            uint4* dh = reinterpret_cast<uint4*>(&Bh[bn * LSTR + bh2 * 16]);
            uint4* dl = reinterpret_cast<uint4*>(&Bl[bn * LSTR + bh2 * 16]);
            dh[0] = sh[0]; dh[1] = sh[1];
            dl[0] = sl[0]; dl[1] = sl[1];
        }
        __syncthreads();
        short8 bhf[4], blf[4];
#pragma unroll
        for (int ni = 0; ni < 4; ni++) {
            int c = C0 + ni * 16 + lr;
            bhf[ni] = *reinterpret_cast<const short8*>(&Bh[c * LSTR + lg * 8]);
            blf[ni] = *reinterpret_cast<const short8*>(&Bl[c * LSTR + lg * 8]);
        }
#pragma unroll
        for (int mi = 0; mi < 4; mi++) {
            int r = R0 + mi * 16 + lr;
            short8 ahf = *reinterpret_cast<const short8*>(&Ah[r * LSTR + lg * 8]);
            short8 alf = *reinterpret_cast<const short8*>(&Al[r * LSTR + lg * 8]);
#pragma unroll
            for (int ni = 0; ni < 4; ni++) {
                acc[mi][ni] = __builtin_amdgcn_mfma_f32_16x16x32_bf16(ahf, bhf[ni], acc[mi][ni], 0, 0, 0);
                acc[mi][ni] = __builtin_amdgcn_mfma_f32_16x16x32_bf16(alf, bhf[ni], acc[mi][ni], 0, 0, 0);
                acc[mi][ni] = __builtin_amdgcn_mfma_f32_16x16x32_bf16(ahf, blf[ni], acc[mi][ni], 0, 0, 0);
            }
        }
    }

    int cn[4];
    float sa[4], da[4];
#pragma unroll
    for (int ni = 0; ni < 4; ni++) {
        cn[ni] = col0 + C0 + ni * 16 + lr;
        sa[ni] = attS[cn[ni]];
        da[ni] = attD[cn[ni]];
    }
    int head0 = (col0 + C0) >> 5;
#pragma unroll
    for (int mi = 0; mi < 4; mi++) {
#pragma unroll
        for (int r = 0; r < 4; r++) {
            int gr = row0 + R0 + mi * 16 + lg * 4 + r;
            float v0 = acc[mi][0][r], v1 = acc[mi][1][r];
            float v2 = acc[mi][2][r], v3 = acc[mi][3][r];
            float ps0 = v0 * sa[0] + v1 * sa[1];
            float pd0 = v0 * da[0] + v1 * da[1];
            float ps1 = v2 * sa[2] + v3 * sa[3];
            float pd1 = v2 * da[2] + v3 * da[3];
#pragma unroll
            for (int m = 1; m <= 8; m <<= 1) {
                ps0 += __shfl_xor(ps0, m);
                pd0 += __shfl_xor(pd0, m);
                ps1 += __shfl_xor(ps1, m);
                pd1 += __shfl_xor(pd1, m);
            }
            if (gr < NN) {
                if (lr == 0) {
                    as1[gr * 8 + head0] = ps0;
                    ad1[gr * 8 + head0] = pd0;
                    as1[gr * 8 + head0 + 1] = ps1;
                    ad1[gr * 8 + head0 + 1] = pd1;
                }
                ushort_t* hp = h1h + (size_t)gr * 256;
                hp[cn[0]] = f2h(v0);
                hp[cn[1]] = f2h(v1);
                hp[cn[2]] = f2h(v2);
                hp[cn[3]] = f2h(v3);
            }
        }
    }
}

// ---- place: derive offsets/deg from bucket, scatter locally (inline bbase) -
__global__ __launch_bounds__(256) void k_place(const int* __restrict__ bcur,
                                               const uint2* __restrict__ ebuf,
                                               int* __restrict__ offset,
                                               int* __restrict__ degt,
                                               int* __restrict__ csr_src) {
    __shared__ int cnt[BW];
    __shared__ int sA[BW];
    __shared__ int sB[BW];
    __shared__ int lcur[BW];
    __shared__ int bsh[256];
    int b = blockIdx.x;
    int t = threadIdx.x;
    int tot = 0;
    if (t < NB) {
        int dNt = (NN - t * BW < BW) ? (NN - t * BW) : BW;
        tot = (bcur[t] - t * CAP) + dNt;
    }
    bsh[t] = tot;
    __syncthreads();
    for (int o = 1; o < 256; o <<= 1) {
        int add = (t >= o) ? bsh[t - o] : 0;
        __syncthreads();
        bsh[t] += add;
        __syncthreads();
    }
    int base = (b > 0) ? bsh[b - 1] : 0;

    int d0 = b * BW;
    int dN = (NN - d0 < BW) ? (NN - d0) : BW;
    cnt[t] = (t < dN) ? 1 : 0;
    cnt[t + 256] = (t + 256 < dN) ? 1 : 0;
    __syncthreads();
    int bcurv = bcur[b];
    for (int i = b * CAP + t; i < bcurv; i += 256)
        atomicAdd(&cnt[ebuf[i].y - d0], 1);
    __syncthreads();
    int o0 = cnt[t], o1 = cnt[t + 256];
    sA[t] = o0; sA[t + 256] = o1;
    __syncthreads();
    int* sp = sA; int* dp = sB;
    for (int o = 1; o < 512; o <<= 1) {
        dp[t] = sp[t] + ((t >= o) ? sp[t - o] : 0);
        int t2 = t + 256;
        dp[t2] = sp[t2] + ((t2 >= o) ? sp[t2 - o] : 0);
        __syncthreads();
        int* tmp = sp; sp = dp; dp = tmp;
    }
    if (t < dN) {
        int off = base + sp[t] - o0;
        offset[d0 + t] = off;
        degt[d0 + t] = o0;
        csr_src[off] = d0 + t;   // self loop
        lcur[t] = off + 1;
    }
    int t2 = t + 256;
    if (t2 < dN) {
        int off = base + sp[t2] - o1;
        offset[d0 + t2] = off;
        degt[d0 + t2] = o1;
        csr_src[off] = d0 + t2;
        lcur[t2] = off + 1;
    }
    __syncthreads();
    for (int i = b * CAP + t; i < bcurv; i += 256) {
        uint2 e = ebuf[i];
        int pos = atomicAdd(&lcur[e.y - d0], 1);
        csr_src[pos] = (int)e.x;
    }
}

// ------- MERGED softmax + aggregate, layer 1 (no-max softmax) --------------
__global__ __launch_bounds__(256) void k_sa1(const int* __restrict__ csr_src,
                                             const int* __restrict__ offset,
                                             const int* __restrict__ degt,
                                             const ushort_t* __restrict__ h1h,
                                             const float* __restrict__ as1,
                                             const float* __restrict__ ad1,
                                             const float* __restrict__ bias1,
                                             ushort_t* __restrict__ h2h) {
    int wave = (blockIdx.x * blockDim.x + threadIdx.x) >> 6;
    int lane = threadIdx.x & 63;
    if (wave >= NN) return;
    int d = wave;
    int beg = offset[d], cnt = degt[d];
    // ---- phase 1: denominator (fixed-shift exp, no running max) ----
    int sub = lane >> 3, h = lane & 7;
    float ad = ad1[d * 8 + h];
    float s = 0.f;
    for (int j = sub; j < cnt; j += 8) {
        int src = csr_src[beg + j];
        float e = as1[src * 8 + h] + ad;
        e = fmaxf(e, SLOPE * e);                 // leaky relu
        s += __expf(e - ESHIFT);
    }
#pragma unroll
    for (int mask = 8; mask <= 32; mask <<= 1) s += __shfl_xor(s, mask);
    float di = 1.f / (s + 1e-16f);
    // ---- remap stats to aggregate layout (head = lane>>3) ----
    int h2 = lane >> 3;
    float dih = __shfl(di, h2);
    float adh = __shfl(ad, h2);
    // ---- phase 2: unnormalized aggregate; scale once at end ----
    int f0 = lane * 4;
    float ax = 0.f, ay = 0.f, az = 0.f, aw = 0.f;
#pragma unroll 4
    for (int j = 0; j < cnt; j++) {
        int src = csr_src[beg + j];
        float e = as1[src * 8 + h2] + adh;
        e = fmaxf(e, SLOPE * e);
        float p = __expf(e - ESHIFT);
        ushort4 hv = *reinterpret_cast<const ushort4*>(h1h + (size_t)src * 256 + f0);
        ax += p * (float)__builtin_bit_cast(_Float16, hv.x);
        ay += p * (float)__builtin_bit_cast(_Float16, hv.y);
        az += p * (float)__builtin_bit_cast(_Float16, hv.z);
        aw += p * (float)__builtin_bit_cast(_Float16, hv.w);
    }
    float4 b = *reinterpret_cast<const float4*>(bias1 + f0);
    float vx = ax * dih + b.x;
    float vy = ay * dih + b.y;
    float vz = az * dih + b.z;
    float vw = aw * dih + b.w;
    vx = (vx > 0.f) ? vx : expm1f(vx);
    vy = (vy > 0.f) ? vy : expm1f(vy);
    vz = (vz > 0.f) ? vz : expm1f(vz);
    vw = (vw > 0.f) ? vw : expm1f(vw);
    ushort4 o;
    o.x = f2h(vx); o.y = f2h(vy); o.z = f2h(vz); o.w = f2h(vw);
    *reinterpret_cast<ushort4*>(h2h + (size_t)d * 256 + f0) = o;
}

// ----------------- GEMM2 (MFMA f16): hh(f16) = h2h @ W2; fused alpha2 ------
__global__ __launch_bounds__(256) void k_gemm2(const ushort_t* __restrict__ A,
                                               const ushort_t* __restrict__ Bht,
                                               const ushort_t* __restrict__ Blt,
                                               const float* __restrict__ attS,
                                               const float* __restrict__ attD,
                                               ushort_t* __restrict__ hh,
                                               float* __restrict__ as2,
                                               float* __restrict__ ad2) {
    __shared__ ushort_t Ash[128 * LSTR];
    __shared__ ushort_t Bh[48 * LSTR];
    __shared__ ushort_t Bl[48 * LSTR];
    int row0 = blockIdx.x * 128;
    int t = threadIdx.x;
    int w = t >> 6, lane = t & 63;
    int lr = lane & 15, lg = lane >> 4;
    int R0 = w * 32;

    f32x4 acc[2][3];
#pragma unroll
    for (int i = 0; i < 2; i++)
#pragma unroll
        for (int j = 0; j < 3; j++) acc[i][j] = (f32x4){0.f, 0.f, 0.f, 0.f};

    for (int it = 0; it < 8; it++) {
        int k0 = it * 32;
        __syncthreads();
#pragma unroll
        for (int i = 0; i < 2; i++) {
            int chunk = t + i * 256;
            int r = chunk >> 2, part = chunk & 3;
            int gr = row0 + r;
            uint4 v = make_uint4(0u, 0u, 0u, 0u);
            if (gr < NN) v = *reinterpret_cast<const uint4*>(A + (size_t)gr * 256 + k0 + part * 8);
            *reinterpret_cast<uint4*>(&Ash[r * LSTR + part * 8]) = v;
        }
        if (t < 192) {
            int bn = t >> 2, part = t & 3;
            *reinterpret_cast<uint4*>(&Bh[bn * LSTR + part * 8]) =
                *reinterpret_cast<const uint4*>(Bht + (size_t)bn * 256 + k0 + part * 8);
            *reinterpret_cast<uint4*>(&Bl[bn * LSTR + part * 8]) =
                *reinterpret_cast<const uint4*>(Blt + (size_t)bn * 256 + k0 + part * 8);
        }
        __syncthreads();
        half8 bhf[3], blf[3];
#pragma unroll
        for (int ni = 0; ni < 3; ni++) {
            int c = ni * 16 + lr;
            bhf[ni] = *reinterpret_cast<const half8*>(&Bh[c * LSTR + lg * 8]);
            blf[ni] = *reinterpret_cast<const half8*>(&Bl[c * LSTR + lg * 8]);
        }
#pragma unroll
        for (int mi = 0; mi < 2; mi++) {
            int r = R0 + mi * 16 + lr;
            half8 af = *reinterpret_cast<const half8*>(&Ash[r * LSTR + lg * 8]);
#pragma unroll
            for (int ni = 0; ni < 3; ni++) {
                acc[mi][ni] = __builtin_amdgcn_mfma_f32_16x16x32_f16(af, bhf[ni], acc[mi][ni], 0, 0, 0);
                acc[mi][ni] = __builtin_amdgcn_mfma_f32_16x16x32_f16(af, blf[ni], acc[mi][ni], 0, 0, 0);
            }
        }
    }

    int cn[3];
    float sa[3], da[3];
#pragma unroll
    for (int ni = 0; ni < 3; ni++) {
        cn[ni] = ni * 16 + lr;
        sa[ni] = (cn[ni] < NCLS) ? attS[cn[ni]] : 0.f;
        da[ni] = (cn[ni] < NCLS) ? attD[cn[ni]] : 0.f;
    }
#pragma unroll
    for (int mi = 0; mi < 2; mi++) {
#pragma unroll
        for (int r = 0; r < 4; r++) {
            int gr = row0 + R0 + mi * 16 + lg * 4 + r;
            float v0 = acc[mi][0][r], v1 = acc[mi][1][r], v2 = acc[mi][2][r];
            float ps = v0 * sa[0] + v1 * sa[1] + v2 * sa[2];
            float pd = v0 * da[0] + v1 * da[1] + v2 * da[2];
#pragma unroll
            for (int m = 1; m <= 8; m <<= 1) {
                ps += __shfl_xor(ps, m);
                pd += __shfl_xor(pd, m);
            }
            if (gr < NN) {
                if (lr == 0) { as2[gr] = ps; ad2[gr] = pd; }
                ushort_t* hp = hh + (size_t)gr * NCLS;
                if (cn[0] < NCLS) hp[cn[0]] = f2h(v0);
                if (cn[1] < NCLS) hp[cn[1]] = f2h(v1);
                if (cn[2] < NCLS) hp[cn[2]] = f2h(v2);
            }
        }
    }
}

// ------- merged softmax + aggregate, layer 2 (no-max softmax) --------------
__global__ __launch_bounds__(256) void k_sa2(const int* __restrict__ csr_src,
                                             const int* __restrict__ offset,
                                             const int* __restrict__ degt,
                                             const ushort_t* __restrict__ hh,
                                             const float* __restrict__ as2,
                                             const float* __restrict__ ad2,
                                             const float* __restrict__ bias2,
                                             float* __restrict__ out) {
    int wave = (blockIdx.x * blockDim.x + threadIdx.x) >> 6;
    int lane = threadIdx.x & 63;
    if (wave >= NN) return;
    int d = wave;
    float ad = ad2[d];
    int beg = offset[d], cnt = degt[d];
    float s = 0.f;
    for (int j = lane; j < cnt; j += 64) {
        int src = csr_src[beg + j];
        float e = as2[src] + ad;
        e = fmaxf(e, SLOPE * e);
        s += __expf(e - ESHIFT);
    }
#pragma unroll
    for (int mask = 1; mask <= 32; mask <<= 1) s += __shfl_xor(s, mask);
    float di = 1.f / (s + 1e-16f);
    int es = lane / 20;
    int ch = lane % 20;
    float a0 = 0.f, a1 = 0.f;
    for (int j0 = 0; j0 < cnt; j0 += 3) {
        int j = j0 + es;
        if (es < 3 && j < cnt) {
            int src = csr_src[beg + j];
            float e = as2[src] + ad;
            e = fmaxf(e, SLOPE * e);
            float w = __expf(e - ESHIFT);
            unsigned v = *reinterpret_cast<const unsigned*>(hh + (size_t)src * NCLS + ch * 2);
            a0 += w * (float)__builtin_bit_cast(_Float16, (ushort_t)(v & 0xFFFFu));
            a1 += w * (float)__builtin_bit_cast(_Float16, (ushort_t)(v >> 16));
        }
    }
    float t0 = __shfl(a0, lane + 20);
    float t1 = __shfl(a0, lane + 40);
    float u0 = __shfl(a1, lane + 20);
    float u1 = __shfl(a1, lane + 40);
    if (lane < 20) {
        float2 o;
        o.x = (a0 + t0 + t1) * di + bias2[ch * 2];
        o.y = (a1 + u0 + u1) * di + bias2[ch * 2 + 1];
        *reinterpret_cast<float2*>(out + (size_t)d * NCLS + ch * 2) = o;
    }
}

extern "C" void kernel_launch(void* const* d_in, const int* in_sizes, int n_in,
                              void* d_out, int out_size, void* d_ws, size_t ws_size,
                              hipStream_t stream) {
    const float* x      = (const float*)d_in[0];
    const int* ei       = (const int*)d_in[1];   // int64 in ref -> int32 on device
    const float* W1     = (const float*)d_in[2];
    const float* att_s1 = (const float*)d_in[3];
    const float* att_d1 = (const float*)d_in[4];
    const float* bias1  = (const float*)d_in[5];
    const float* W2     = (const float*)d_in[6];
    const float* att_s2 = (const float*)d_in[7];
    const float* att_d2 = (const float*)d_in[8];
    const float* bias2  = (const float*)d_in[9];
    float* out = (float*)d_out;

    char* ws = (char*)d_ws;
    size_t off = 0;
    auto alloc = [&](size_t bytes) -> void* {
        void* p = ws + off;
        off = (off + bytes + 255) & ~(size_t)255;
        return p;
    };
    ushort_t* h1h = (ushort_t*)alloc((size_t)NN * 256 * 2);
    ushort_t* h2h = (ushort_t*)alloc((size_t)NN * 256 * 2);
    ushort_t* hh  = (ushort_t*)alloc((size_t)NN * NCLS * 2);
    float* as1  = (float*)alloc((size_t)NN * 8 * 4);
    float* ad1  = (float*)alloc((size_t)NN * 8 * 4);
    float* as2  = (float*)alloc((size_t)NN * 4);
    float* ad2  = (float*)alloc((size_t)NN * 4);
    int* degt   = (int*)alloc((size_t)NN * 4);
    int* offs   = (int*)alloc((size_t)(NN + 1) * 4);
    int* csr    = (int*)alloc((size_t)ETOT * 4);
    uint2* ebuf = (uint2*)alloc((size_t)NB * CAP * 8);
    int* bcur   = (int*)alloc((size_t)NB * 4 + 256);
    ushort_t* W1ht = (ushort_t*)alloc((size_t)256 * 256 * 2);
    ushort_t* W1lt = (ushort_t*)alloc((size_t)256 * 256 * 2);
    ushort_t* W2ht = (ushort_t*)alloc((size_t)48 * 256 * 2);
    ushort_t* W2lt = (ushort_t*)alloc((size_t)48 * 256 * 2);

    k_splitW<<<305, 256, 0, stream>>>(W1, W1ht, W1lt, W2, W2ht, W2lt, bcur);
    k_g1b<<<NBB + GB1, 256, 0, stream>>>(x, W1ht, W1lt, att_s1, att_d1, h1h, as1, ad1,
                                         ei, bcur, ebuf);
    k_place<<<NB, 256, 0, stream>>>(bcur, ebuf, offs, degt, csr);
    k_sa1<<<(NN + 3) / 4, 256, 0, stream>>>(csr, offs, degt, h1h, as1, ad1, bias1, h2h);
    k_gemm2<<<(NN + 127) / 128, 256, 0, stream>>>(h2h, W2ht, W2lt, att_s2, att_d2, hh, as2, ad2);
    k_sa2<<<(NN + 3) / 4, 256, 0, stream>>>(csr, offs, degt, hh, as2, ad2, bias2, out);
}